// Round 1
// 872.548 us; speedup vs baseline: 1.2660x; 1.2660x over previous
//
#include <hip/hip_runtime.h>
#include <hip/hip_bf16.h>
#include <math.h>

#define HH    4
#define NSEQ  1024
#define KVD   960    // true KV dim
#define KVP   1024   // padded KV dim (zero pad) so every tile dim is 128-divisible
#define BATCH 8
#define ECAT  1024   // concat of branch channel dims (960 real, 64 pad rows)

static constexpr float EPS = 1e-5f;

typedef __attribute__((ext_vector_type(8))) short short8;   // 8 bf16
typedef __attribute__((ext_vector_type(4))) short short4e;  // 4 bf16
typedef __attribute__((ext_vector_type(4))) float f32x4;    // MFMA C/D frag

__device__ __forceinline__ short f2bf(float x) {
    union { __hip_bfloat16 h; short s; } u;
    u.h = __float2bfloat16(x);
    return u.s;
}
__device__ __forceinline__ short8 cvt8(const float* __restrict__ g) {
    const float4 a = *(const float4*)g;
    const float4 b = *(const float4*)(g + 4);
    short8 t;
    t[0] = f2bf(a.x); t[1] = f2bf(a.y); t[2] = f2bf(a.z); t[3] = f2bf(a.w);
    t[4] = f2bf(b.x); t[5] = f2bf(b.y); t[6] = f2bf(b.z); t[7] = f2bf(b.w);
    return t;
}

// ---- one-time input converts: 13 segments in ONE launch ----------------------
struct ConvJobs {
    const float* src[13];
    short*       dst[13];
    long         cum[14];    // cum[i] = start (in short8 units) of job i; cum[13] = total
    float*       statsAcc;   // zero-init side effect (block 0)
    int          nAcc;
};

__global__ void conv_mega_kernel(ConvJobs J)
{
    if (blockIdx.x == 0 && threadIdx.x < (unsigned)J.nAcc)
        J.statsAcc[threadIdx.x] = 0.f;
    const long u = (long)blockIdx.x * 256 + threadIdx.x;
    if (u >= J.cum[13]) return;
    int sg = 0;
    while (u >= J.cum[sg + 1]) ++sg;
    const long l = u - J.cum[sg];
    *(short8*)(J.dst[sg] + l * 8) = cvt8(J.src[sg] + l * 8);
}

// WK/WV: [H][960][960] fp32 -> [H][1024][960] bf16, rows 960..1023 zeroed
__global__ void conv_padw_kernel(const float* __restrict__ src, short* __restrict__ dst)
{
    const long u = (long)blockIdx.x * 256 + threadIdx.x;  // one short8 per thread
    const int cpr = KVD / 8;                              // 120
    const int c8  = (int)(u % cpr) * 8;
    const int row = (int)((u / cpr) % KVP);
    const int h   = (int)(u / ((long)cpr * KVP));
    short8 t = (short8){0,0,0,0,0,0,0,0};
    if (row < KVD) t = cvt8(src + ((long)h * KVD + row) * KVD + c8);
    *(short8*)(dst + ((long)h * KVP + row) * KVD + c8) = t;
}

// ---- async LDS staging: ROWS x 32 bf16, UNPADDED 64B rows, chunk-XOR swizzle.
template<int ROWS>
__device__ __forceinline__ void stage_async(short (*dst)[32], const short* __restrict__ src,
                                            int ld, int w, int lane)
{
    #pragma unroll
    for (int p = 0; p < ROWS / 64; ++p) {
        const int rbase = p * 64 + w * 16;
        const int row   = rbase + (lane >> 2);
        const int c16l  = ((lane & 3) - row) & 3;   // logical chunk landing at this slot
        const short* g  = src + (long)row * ld + c16l * 8;
        __builtin_amdgcn_global_load_lds(
            (const __attribute__((address_space(1))) void*)g,
            (__attribute__((address_space(3))) void*)&dst[rbase][0],
            16, 0, 0);
    }
}

// ---------------------------------------------------------------------------
// bf16-MFMA NT GEMM, 1D grid with XCD-clustered swizzle, async LDS staging.
// C[M,Nc] = alpha * sum_ib A_ib[M,K] @ B_ib[Nc,K]^T   (K contiguous both sides)
// STATS=1 (S GEMM only): per-tile sum/sumsq of real rows (<KVD) accumulated by
// branch group via device atomics (branch from m0; concat row offsets 0/512/768/896).
// ---------------------------------------------------------------------------
template<int TM, int TN, typename TC, int STATS = 0>
__global__ __launch_bounds__(256) void mfma_nt(
    const short* __restrict__ A, const short* __restrict__ B, TC* __restrict__ C,
    int lda, int ldb, int ldc, int K, float alpha, int inner, long sA, long sB,
    long zAh, long zAg, long zBh, long zBg, long zCh, long zCg,
    int splitH, int gx, int gy, float* __restrict__ statsAcc)
{
    constexpr int MT = TM / 32;
    constexpr int NT = TN / 32;
    __shared__ short As[TM][32];
    __shared__ short Bs[TN][32];

    const int bps = gx * gy;
    const int Z   = gridDim.x / bps;
    int z, r;
    if ((Z & 7) == 0) {
        const int xcd = blockIdx.x & 7;
        const int j   = blockIdx.x >> 3;
        const int spx = Z >> 3;             // slices per XCD
        z = xcd * spx + j / bps;
        r = j % bps;
    } else {
        z = blockIdx.x / bps;
        r = blockIdx.x % bps;
    }
    const int x = r % gx, y = r / gx;
    int h, g;
    if (splitH) { h = z & (HH - 1); g = z >> 2; }
    else        { h = 0;            g = z;      }
    A += (long)h * zAh + (long)g * zAg;
    B += (long)h * zBh + (long)g * zBg;
    C += (long)h * zCh + (long)g * zCg;

    const int tid  = threadIdx.x;
    const int lane = tid & 63;
    const int w    = tid >> 6;
    const int wr   = w >> 1;
    const int wc   = w & 1;
    const int quad = lane >> 4;
    const int l16  = lane & 15;
    const long m0  = (long)y * TM;
    const long n0  = (long)x * TN;

    f32x4 acc[MT][NT];
    #pragma unroll
    for (int i = 0; i < MT; ++i)
        #pragma unroll
        for (int j2 = 0; j2 < NT; ++j2)
            acc[i][j2] = (f32x4){0.f, 0.f, 0.f, 0.f};

    for (int ib = 0; ib < inner; ++ib) {
        const short* Ab = A + (long)ib * sA + m0 * lda;
        const short* Bb = B + (long)ib * sB + n0 * ldb;
        for (int k0 = 0; k0 < K; k0 += 32) {
            stage_async<TM>(As, Ab + k0, lda, w, lane);
            stage_async<TN>(Bs, Bb + k0, ldb, w, lane);
            __syncthreads();   // drains vmcnt -> DMA'd LDS data visible
            short8 af[MT], bfr[NT];
            #pragma unroll
            for (int i = 0; i < MT; ++i) {
                const int rowA = wr * (TM / 2) + i * 16 + l16;
                af[i] = *(const short8*)&As[rowA][((quad + rowA) & 3) * 8];
            }
            #pragma unroll
            for (int j2 = 0; j2 < NT; ++j2) {
                const int rowB = wc * (TN / 2) + j2 * 16 + l16;
                bfr[j2] = *(const short8*)&Bs[rowB][((quad + rowB) & 3) * 8];
            }
            #pragma unroll
            for (int i = 0; i < MT; ++i)
                #pragma unroll
                for (int j2 = 0; j2 < NT; ++j2)
                    acc[i][j2] = __builtin_amdgcn_mfma_f32_16x16x32_bf16(
                        af[i], bfr[j2], acc[i][j2], 0, 0, 0);
            __syncthreads();
        }
    }

    // C/D layout: col = lane&15, row = (lane>>4)*4 + reg   [m89-verified]
    float s = 0.f, ss = 0.f;
    #pragma unroll
    for (int i = 0; i < MT; ++i) {
        #pragma unroll
        for (int j2 = 0; j2 < NT; ++j2) {
            const long row = m0 + wr * (TM / 2) + i * 16 + quad * 4;
            const long col = n0 + wc * (TN / 2) + j2 * 16 + l16;
            #pragma unroll
            for (int rr = 0; rr < 4; ++rr) {
                const float v = alpha * acc[i][j2][rr];
                if constexpr (sizeof(TC) == 4)
                    C[(row + rr) * ldc + col] = v;
                else
                    C[(row + rr) * ldc + col] = f2bf(v);
                if constexpr (STATS) {
                    if (row + rr < KVD) { s += v; ss += v * v; }  // pad cols are exact 0
                }
            }
        }
    }
    if constexpr (STATS) {
        float* red = (float*)&As[0][0];     // 8 KB >= 512 floats (TM=128 only)
        red[tid] = s; red[256 + tid] = ss;
        __syncthreads();
        for (int o = 128; o > 0; o >>= 1) {
            if (tid < o) { red[tid] += red[tid + o]; red[256 + tid] += red[256 + tid + o]; }
            __syncthreads();
        }
        if (tid == 0) {
            const int bidx = (m0 >= 896) ? 0 : (m0 >= 768) ? 1 : (m0 >= 512) ? 2 : 3;
            atomicAdd(&statsAcc[((long)z * 4 + bidx) * 2],     red[0]);
            atomicAdd(&statsAcc[((long)z * 4 + bidx) * 2 + 1], red[256]);
        }
    }
}

// ---- stats finalize: one block, one thread per (z, branch) group -------------
__global__ void stats_final_kernel(float* __restrict__ acc, float* __restrict__ stats,
                                   int ngroups)
{
    const int t = threadIdx.x;
    if (t >= ngroups) return;
    const int dftab[4] = {64, 128, 256, 512};
    const float n = (float)(dftab[t & 3] * KVD);
    const float s  = acc[2 * t];
    const float ss = acc[2 * t + 1];
    const float mean = s / n;
    const float var  = ss / n - mean * mean;
    stats[2 * t]     = mean;
    stats[2 * t + 1] = rsqrtf(var + EPS);
    acc[2 * t] = 0.f; acc[2 * t + 1] = 0.f;   // ready for next b0 iteration
}

// ---- softmax over real 960 cols; bf16 A-operand out; pad cols AND rows zeroed.
// grid (ECAT, Z), block 256; branch resolved from concat row.
__global__ void softmax_kernel(const float* __restrict__ S,
                               short* __restrict__ Sa,
                               const float* __restrict__ stats)
{
    const int row = blockIdx.x;          // 0..1023 concat rows (>=960 = pad)
    const int y   = blockIdx.y;
    const int t   = threadIdx.x;
    short* orow = Sa + ((long)y * ECAT + row) * KVP;
    if (row >= KVD) {                    // zero pad row (clean B-operand for Ch)
        *(short4e*)(orow + 4 * t) = (short4e){0, 0, 0, 0};
        return;
    }
    const int bidx = (row >= 896) ? 0 : (row >= 768) ? 1 : (row >= 512) ? 2 : 3;
    const float mean = stats[((long)y * 4 + bidx) * 2];
    const float rstd = stats[((long)y * 4 + bidx) * 2 + 1];
    const float* srow = S + ((long)y * ECAT + row) * KVP;

    const bool real = (t < KVD / 4);     // threads 0..239 hold real cols (4 each)
    float x[4];
    float mx = -1e30f;
    if (real) {
        const float4 v = *(const float4*)(srow + 4 * t);
        x[0] = (v.x - mean) * rstd; x[1] = (v.y - mean) * rstd;
        x[2] = (v.z - mean) * rstd; x[3] = (v.w - mean) * rstd;
        mx = fmaxf(fmaxf(x[0], x[1]), fmaxf(x[2], x[3]));
    }
    __shared__ float red[256];
    red[t] = mx; __syncthreads();
    for (int o = 128; o > 0; o >>= 1) {
        if (t < o) red[t] = fmaxf(red[t], red[t + o]);
        __syncthreads();
    }
    mx = red[0];
    __syncthreads();

    float e[4] = {0.f, 0.f, 0.f, 0.f};
    float sum = 0.f;
    if (real) {
        e[0] = __expf(x[0] - mx); e[1] = __expf(x[1] - mx);
        e[2] = __expf(x[2] - mx); e[3] = __expf(x[3] - mx);
        sum = e[0] + e[1] + e[2] + e[3];
    }
    red[t] = sum; __syncthreads();
    for (int o = 128; o > 0; o >>= 1) {
        if (t < o) red[t] += red[t + o];
        __syncthreads();
    }
    const float inv = 1.0f / red[0];
    short4e o4;
    o4[0] = f2bf(e[0] * inv); o4[1] = f2bf(e[1] * inv);
    o4[2] = f2bf(e[2] * inv); o4[3] = f2bf(e[3] * inv);
    *(short4e*)(orow + 4 * t) = o4;
}

// ---------------------------------------------------------------------------
extern "C" void kernel_launch(void* const* d_in, const int* in_sizes, int n_in,
                              void* d_out, int out_size, void* d_ws, size_t ws_size,
                              hipStream_t stream)
{
    (void)in_sizes; (void)n_in; (void)out_size;
    const float* emb[4]  = {(const float*)d_in[0], (const float*)d_in[1],
                            (const float*)d_in[2], (const float*)d_in[3]};
    const float* emb_all = (const float*)d_in[4];
    const float* WQ[4]   = {(const float*)d_in[5], (const float*)d_in[6],
                            (const float*)d_in[7], (const float*)d_in[8]};
    const float* WK      = (const float*)d_in[9];
    const float* WV      = (const float*)d_in[10];
    const float* WO[4]   = {(const float*)d_in[11], (const float*)d_in[12],
                            (const float*)d_in[13], (const float*)d_in[14]};
    float* out = (float*)d_out;

    const int dfs[4]    = {64, 128, 256, 512};
    const int rowoff[4] = {896, 768, 512, 0};   // concat offsets (tile-aligned)
    const long N = NSEQ;

    // ---- workspace budget
    const long eAll = (long)BATCH * N * KVD;
    const long eWKp = (long)HH * KVP * KVD;
    long preBytes = eAll * 2 + 2 * eWKp * 2;
    for (int br = 0; br < 4; ++br)
        preBytes += ((long)BATCH * N * dfs[br] + (long)HH * dfs[br] * dfs[br]
                    + (long)dfs[br] * dfs[br]) * 2;
    const long perG = (long)HH * KVP * N * 2      // KT
                    + (long)HH * N * KVP * 2      // V
                    + (long)HH * ECAT * N * 2     // Qcat
                    + (long)HH * ECAT * KVP * 4   // Scat (Chcat aliases this)
                    + (long)HH * ECAT * KVP * 2   // Sacat
                    + (long)HH * 4 * 4 * 4;       // stats bufs
    int G = 8;
    while (G > 1 && preBytes + (long)G * perG + 65536 > (long)ws_size) G >>= 1;

    // ---- carve workspace
    char* p = (char*)d_ws;
    short* embAllp = (short*)p; p += eAll * 2;
    short* embp[4]; short* WQp[4]; short* WOp[4];
    for (int br = 0; br < 4; ++br) { embp[br] = (short*)p; p += (long)BATCH * N * dfs[br] * 2; }
    for (int br = 0; br < 4; ++br) { WQp[br]  = (short*)p; p += (long)HH * dfs[br] * dfs[br] * 2; }
    short* WKp = (short*)p; p += eWKp * 2;
    short* WVp = (short*)p; p += eWKp * 2;
    for (int br = 0; br < 4; ++br) { WOp[br]  = (short*)p; p += (long)dfs[br] * dfs[br] * 2; }
    short* KTb = (short*)p; p += (long)G * HH * KVP * N * 2;
    short* Vb  = (short*)p; p += (long)G * HH * N * KVP * 2;
    short* Qb  = (short*)p; p += (long)G * HH * ECAT * N * 2;    // Qcat
    float* Sb  = (float*)p; p += (long)G * HH * ECAT * KVP * 4;  // Scat
    short* Sab = (short*)p; p += (long)G * HH * ECAT * KVP * 2;  // Sacat
    float* statsAcc = (float*)p; p += (long)G * HH * 4 * 2 * 4;
    float* statsb   = (float*)p; p += (long)G * HH * 4 * 2 * 4;
    short* Chb = (short*)Sb;   // Chcat aliases Scat (Scat fully consumed by softmax)

    // ---- one mega-convert launch (13 segments) + padded WK/WV converts
    {
        ConvJobs J;
        long cum = 0; int sg = 0;
        auto addJob = [&](const float* src, short* dst, long nfloat) {
            J.src[sg] = src; J.dst[sg] = dst; J.cum[sg] = cum;
            cum += nfloat / 8; ++sg;
        };
        addJob(emb_all, embAllp, eAll);
        for (int br = 0; br < 4; ++br) addJob(emb[br], embp[br], (long)BATCH * N * dfs[br]);
        for (int br = 0; br < 4; ++br) addJob(WQ[br], WQp[br], (long)HH * dfs[br] * dfs[br]);
        for (int br = 0; br < 4; ++br) addJob(WO[br], WOp[br], (long)dfs[br] * dfs[br]);
        J.cum[13] = cum;
        J.statsAcc = statsAcc;
        J.nAcc = G * HH * 4 * 2;
        conv_mega_kernel<<<dim3((unsigned)((cum + 255) / 256)), dim3(256), 0, stream>>>(J);
        const int padw_blocks = HH * KVP * (KVD / 8) / 256;   // 1920
        conv_padw_kernel<<<dim3(padw_blocks), dim3(256), 0, stream>>>(WK, WKp);
        conv_padw_kernel<<<dim3(padw_blocks), dim3(256), 0, stream>>>(WV, WVp);
    }

    const float scale = 1.0f / sqrtf((float)KVD);
    long outBase[4];
    {
        long acc = 0;
        for (int br = 0; br < 4; ++br) { outBase[br] = acc; acc += (long)BATCH * N * dfs[br]; }
    }

    const dim3 blk(256);
    for (int b0 = 0; b0 < BATCH; b0 += G) {
        const int Z = G * HH;
        const short* embA = embAllp + (long)b0 * N * KVD;

        // KT[g][h][j(1024)][n] = sum_k WKp[h][j][k] embA[g][n][k]   M=KVP,Nc=N,K=KVD
        mfma_nt<128, 128, short><<<dim3(8 * 8 * Z), blk, 0, stream>>>(
            WKp, embA, KTb, KVD, KVD, (int)N, KVD, 1.0f, 1, 0, 0,
            (long)KVP * KVD, 0,
            0, (long)N * KVD,
            (long)KVP * N, (long)HH * KVP * N, 1, 8, 8, nullptr);

        // V[g][h][n][j(1024)] = sum_k embA[g][n][k] WVp[h][j][k]    M=N,Nc=KVP,K=KVD
        mfma_nt<128, 128, short><<<dim3(8 * 8 * Z), blk, 0, stream>>>(
            embA, WVp, Vb, KVD, KVD, KVP, KVD, 1.0f, 1, 0, 0,
            0, (long)N * KVD,
            (long)KVP * KVD, 0,
            (long)N * KVP, (long)HH * N * KVP, 1, 8, 8, nullptr);

        // Q (per branch) written into concat rows of Qcat[g][h][ECAT][N]
        for (int br = 0; br < 4; ++br) {
            const int df = dfs[br];
            const short* embB = embp[br] + (long)b0 * N * df;
            short* Qdst = Qb + (long)rowoff[br] * N;
            if (df >= 128)
                mfma_nt<128, 128, short><<<dim3(8 * (df / 128) * Z), blk, 0, stream>>>(
                    WQp[br], embB, Qdst, df, df, (int)N, df, 1.0f, 1, 0, 0,
                    (long)df * df, 0, 0, (long)N * df,
                    (long)ECAT * N, (long)HH * ECAT * N, 1, 8, df / 128, nullptr);
            else
                mfma_nt<64, 128, short><<<dim3(8 * 1 * Z), blk, 0, stream>>>(
                    WQp[br], embB, Qdst, df, df, (int)N, df, 1.0f, 1, 0, 0,
                    (long)df * df, 0, 0, (long)N * df,
                    (long)ECAT * N, (long)HH * ECAT * N, 1, 8, 1, nullptr);
        }

        // S merged: S[g][h][e_cat][j] = scale * sum_n Qcat[e][n] KT[j][n]
        //   M=ECAT, Nc=KVP, K=N; fused per-branch stats via atomics (STATS=1)
        mfma_nt<128, 128, float, 1><<<dim3(8 * 8 * Z), blk, 0, stream>>>(
            Qb, KTb, Sb, (int)N, (int)N, KVP, (int)N, scale, 1, 0, 0,
            (long)ECAT * N, (long)HH * ECAT * N,
            (long)KVP * N, (long)HH * KVP * N,
            (long)ECAT * KVP, (long)HH * ECAT * KVP, 1, 8, 8, statsAcc);

        stats_final_kernel<<<dim3(1), dim3(128), 0, stream>>>(statsAcc, statsb, Z * 4);
        softmax_kernel<<<dim3(ECAT, Z), dim3(256), 0, stream>>>(Sb, Sab, statsb);

        // Ch merged: Ch[g][h][n][e_cat] = sum_j V[n][j] Sa[e_cat][j]
        //   M=N, Nc=ECAT, K=KVP  (writes over Scat alias — Scat fully consumed)
        mfma_nt<128, 128, short><<<dim3(8 * 8 * Z), blk, 0, stream>>>(
            Vb, Sab, Chb, KVP, KVP, ECAT, KVP, 1.0f, 1, 0, 0,
            (long)N * KVP, (long)HH * N * KVP,
            (long)ECAT * KVP, (long)HH * ECAT * KVP,
            (long)N * ECAT, (long)HH * N * ECAT, 1, 8, 8, nullptr);

        // O (per branch): O[b0+g][n][f] = (1/H) sum_h sum_e Ch[g][h][n][e_off+e] WO[f][e]
        //   A = Chcat column slice (lda=ECAT), inner=HH, Z=G
        for (int br = 0; br < 4; ++br) {
            const int df = dfs[br];
            const short* Asrc = Chb + rowoff[br];
            float* Cout = out + outBase[br] + (long)b0 * N * df;
            if (df >= 128)
                mfma_nt<128, 128, float><<<dim3((df / 128) * 8 * G), blk, 0, stream>>>(
                    Asrc, WOp[br], Cout, ECAT, df, df, df, 1.0f / HH, HH,
                    (long)N * ECAT, 0,
                    0, (long)HH * N * ECAT, 0, 0,
                    0, (long)N * df, 0, df / 128, 8, nullptr);
            else
                mfma_nt<128, 64, float><<<dim3(1 * 8 * G), blk, 0, stream>>>(
                    Asrc, WOp[br], Cout, ECAT, df, df, df, 1.0f / HH, HH,
                    (long)N * ECAT, 0,
                    0, (long)HH * N * ECAT, 0, 0,
                    0, (long)N * df, 0, 1, 8, nullptr);
        }
    }
}

// Round 2
// 700.789 us; speedup vs baseline: 1.5762x; 1.2451x over previous
//
#include <hip/hip_runtime.h>
#include <hip/hip_bf16.h>
#include <math.h>

#define HH    4
#define NSEQ  1024
#define KVD   960    // true KV dim
#define KVP   1024   // padded KV dim (zero pad) so every tile dim is 128-divisible
#define BATCH 8
#define ECAT  1024   // concat of branch channel dims (960 real, 64 pad rows)

static constexpr float EPS = 1e-5f;

typedef __attribute__((ext_vector_type(8))) short short8;   // 8 bf16
typedef __attribute__((ext_vector_type(4))) short short4e;  // 4 bf16
typedef __attribute__((ext_vector_type(4))) float f32x4;    // MFMA C/D frag

__device__ __forceinline__ short f2bf(float x) {
    union { __hip_bfloat16 h; short s; } u;
    u.h = __float2bfloat16(x);
    return u.s;
}
__device__ __forceinline__ short8 cvt8(const float* __restrict__ g) {
    const float4 a = *(const float4*)g;
    const float4 b = *(const float4*)(g + 4);
    short8 t;
    t[0] = f2bf(a.x); t[1] = f2bf(a.y); t[2] = f2bf(a.z); t[3] = f2bf(a.w);
    t[4] = f2bf(b.x); t[5] = f2bf(b.y); t[6] = f2bf(b.z); t[7] = f2bf(b.w);
    return t;
}

// ---- one-time input converts: 15 segments (13 plain + 2 padded-W) in ONE launch
struct ConvJobs {
    const float* src[15];
    short*       dst[15];
    long         cum[16];    // cum[i] = start (short8 units) of job i; cum[15] = total
    int          type[15];   // 0 = plain copy, 1 = padded WK/WV layout
    float*       statsAcc;   // zero-init side effect (block 0)
    int          nAcc;
};

__global__ void conv_all_kernel(ConvJobs J)
{
    if (blockIdx.x == 0 && threadIdx.x < (unsigned)J.nAcc)
        J.statsAcc[threadIdx.x] = 0.f;
    const long u = (long)blockIdx.x * 256 + threadIdx.x;
    if (u >= J.cum[15]) return;
    int sg = 0;
    while (u >= J.cum[sg + 1]) ++sg;
    const long l = u - J.cum[sg];
    if (J.type[sg] == 0) {
        *(short8*)(J.dst[sg] + l * 8) = cvt8(J.src[sg] + l * 8);
    } else {
        // [H][960][960] fp32 -> [H][1024][960] bf16, rows 960..1023 zeroed
        const int cpr = KVD / 8;                              // 120
        const int c8  = (int)(l % cpr) * 8;
        const int row = (int)((l / cpr) % KVP);
        const int h   = (int)(l / ((long)cpr * KVP));
        short8 t = (short8){0,0,0,0,0,0,0,0};
        if (row < KVD) t = cvt8(J.src[sg] + ((long)h * KVD + row) * KVD + c8);
        *(short8*)(J.dst[sg] + ((long)h * KVP + row) * KVD + c8) = t;
    }
}

// ---- async LDS staging: ROWS x 32 bf16, UNPADDED 64B rows, chunk-XOR swizzle.
template<int ROWS>
__device__ __forceinline__ void stage_async(short (*dst)[32], const short* __restrict__ src,
                                            int ld, int w, int lane)
{
    #pragma unroll
    for (int p = 0; p < ROWS / 64; ++p) {
        const int rbase = p * 64 + w * 16;
        const int row   = rbase + (lane >> 2);
        const int c16l  = ((lane & 3) - row) & 3;   // logical chunk landing at this slot
        const short* g  = src + (long)row * ld + c16l * 8;
        __builtin_amdgcn_global_load_lds(
            (const __attribute__((address_space(1))) void*)g,
            (__attribute__((address_space(3))) void*)&dst[rbase][0],
            16, 0, 0);
    }
}

// ---------------------------------------------------------------------------
// Job descriptor for the multi-GEMM (job-table) launches. Geometry identical
// to the round-1 standalone launches; blkBase maps blockIdx -> (job, tile).
// ---------------------------------------------------------------------------
struct GemmJob {
    const short* A; const short* B; void* C;
    float alpha;
    int lda, ldb, ldc, K, inner, gx, gy, Z, splitH, cfg, blkBase, pad0;
    long sA, sB, zAh, zAg, zBh, zBg, zCh, zCg;
};
struct GemmJobs { GemmJob j[8]; int njobs; };

// Shared GEMM body (no stats). C[M,Nc] = alpha * sum_ib A[M,K] @ B[Nc,K]^T
template<int TM, int TN, typename TC>
__device__ __forceinline__ void gemm_body(const GemmJob& job, int lb,
                                          short (*As)[32], short (*Bs)[32])
{
    constexpr int MT = TM / 32;
    constexpr int NT = TN / 32;
    const short* A = job.A;
    const short* B = job.B;
    TC* C = (TC*)job.C;
    const int bps = job.gx * job.gy;
    const int Z   = job.Z;
    int z, r;
    if ((Z & 7) == 0) {
        const int xcd = lb & 7;
        const int j   = lb >> 3;
        const int spx = Z >> 3;
        z = xcd * spx + j / bps;
        r = j % bps;
    } else {
        z = lb / bps;
        r = lb % bps;
    }
    const int x = r % job.gx, y = r / job.gx;
    int h, g;
    if (job.splitH) { h = z & (HH - 1); g = z >> 2; }
    else            { h = 0;            g = z;      }
    A += (long)h * job.zAh + (long)g * job.zAg;
    B += (long)h * job.zBh + (long)g * job.zBg;
    C += (long)h * job.zCh + (long)g * job.zCg;

    const int tid  = threadIdx.x;
    const int lane = tid & 63;
    const int w    = tid >> 6;
    const int wr   = w >> 1;
    const int wc   = w & 1;
    const int quad = lane >> 4;
    const int l16  = lane & 15;
    const long m0  = (long)y * TM;
    const long n0  = (long)x * TN;

    f32x4 acc[MT][NT];
    #pragma unroll
    for (int i = 0; i < MT; ++i)
        #pragma unroll
        for (int j2 = 0; j2 < NT; ++j2)
            acc[i][j2] = (f32x4){0.f, 0.f, 0.f, 0.f};

    for (int ib = 0; ib < job.inner; ++ib) {
        const short* Ab = A + (long)ib * job.sA + m0 * job.lda;
        const short* Bb = B + (long)ib * job.sB + n0 * job.ldb;
        for (int k0 = 0; k0 < job.K; k0 += 32) {
            stage_async<TM>(As, Ab + k0, job.lda, w, lane);
            stage_async<TN>(Bs, Bb + k0, job.ldb, w, lane);
            __syncthreads();
            short8 af[MT], bfr[NT];
            #pragma unroll
            for (int i = 0; i < MT; ++i) {
                const int rowA = wr * (TM / 2) + i * 16 + l16;
                af[i] = *(const short8*)&As[rowA][((quad + rowA) & 3) * 8];
            }
            #pragma unroll
            for (int j2 = 0; j2 < NT; ++j2) {
                const int rowB = wc * (TN / 2) + j2 * 16 + l16;
                bfr[j2] = *(const short8*)&Bs[rowB][((quad + rowB) & 3) * 8];
            }
            #pragma unroll
            for (int i = 0; i < MT; ++i)
                #pragma unroll
                for (int j2 = 0; j2 < NT; ++j2)
                    acc[i][j2] = __builtin_amdgcn_mfma_f32_16x16x32_bf16(
                        af[i], bfr[j2], acc[i][j2], 0, 0, 0);
            __syncthreads();
        }
    }

    #pragma unroll
    for (int i = 0; i < MT; ++i) {
        #pragma unroll
        for (int j2 = 0; j2 < NT; ++j2) {
            const long row = m0 + wr * (TM / 2) + i * 16 + quad * 4;
            const long col = n0 + wc * (TN / 2) + j2 * 16 + l16;
            #pragma unroll
            for (int rr = 0; rr < 4; ++rr) {
                const float v = job.alpha * acc[i][j2][rr];
                if constexpr (sizeof(TC) == 4)
                    C[(row + rr) * job.ldc + col] = v;
                else
                    C[(row + rr) * job.ldc + col] = f2bf(v);
            }
        }
    }
}

template<typename TC>
__global__ __launch_bounds__(256) void mfma_jt(GemmJobs J)
{
    __shared__ short As[128][32];
    __shared__ short Bs[128][32];
    const int bid = blockIdx.x;
    int ji = 0;
    while (ji + 1 < J.njobs && bid >= J.j[ji + 1].blkBase) ++ji;
    const GemmJob& job = J.j[ji];
    const int lb = bid - job.blkBase;
    switch (job.cfg) {
        case 0: gemm_body<128, 128, TC>(job, lb, As, Bs); break;
        case 1: gemm_body<128,  64, TC>(job, lb, As, Bs); break;
        default: gemm_body<64, 128, TC>(job, lb, As, Bs); break;
    }
}

// ---------------------------------------------------------------------------
// Dedicated kernel for S (fused instance-norm stats) and Ch — identical to the
// round-1 verified mfma_nt.
// ---------------------------------------------------------------------------
template<int TM, int TN, typename TC, int STATS = 0>
__global__ __launch_bounds__(256) void mfma_nt(
    const short* __restrict__ A, const short* __restrict__ B, TC* __restrict__ C,
    int lda, int ldb, int ldc, int K, float alpha, int inner, long sA, long sB,
    long zAh, long zAg, long zBh, long zBg, long zCh, long zCg,
    int splitH, int gx, int gy, float* __restrict__ statsAcc)
{
    constexpr int MT = TM / 32;
    constexpr int NT = TN / 32;
    __shared__ short As[TM][32];
    __shared__ short Bs[TN][32];

    const int bps = gx * gy;
    const int Z   = gridDim.x / bps;
    int z, r;
    if ((Z & 7) == 0) {
        const int xcd = blockIdx.x & 7;
        const int j   = blockIdx.x >> 3;
        const int spx = Z >> 3;
        z = xcd * spx + j / bps;
        r = j % bps;
    } else {
        z = blockIdx.x / bps;
        r = blockIdx.x % bps;
    }
    const int x = r % gx, y = r / gx;
    int h, g;
    if (splitH) { h = z & (HH - 1); g = z >> 2; }
    else        { h = 0;            g = z;      }
    A += (long)h * zAh + (long)g * zAg;
    B += (long)h * zBh + (long)g * zBg;
    C += (long)h * zCh + (long)g * zCg;

    const int tid  = threadIdx.x;
    const int lane = tid & 63;
    const int w    = tid >> 6;
    const int wr   = w >> 1;
    const int wc   = w & 1;
    const int quad = lane >> 4;
    const int l16  = lane & 15;
    const long m0  = (long)y * TM;
    const long n0  = (long)x * TN;

    f32x4 acc[MT][NT];
    #pragma unroll
    for (int i = 0; i < MT; ++i)
        #pragma unroll
        for (int j2 = 0; j2 < NT; ++j2)
            acc[i][j2] = (f32x4){0.f, 0.f, 0.f, 0.f};

    for (int ib = 0; ib < inner; ++ib) {
        const short* Ab = A + (long)ib * sA + m0 * lda;
        const short* Bb = B + (long)ib * sB + n0 * ldb;
        for (int k0 = 0; k0 < K; k0 += 32) {
            stage_async<TM>(As, Ab + k0, lda, w, lane);
            stage_async<TN>(Bs, Bb + k0, ldb, w, lane);
            __syncthreads();
            short8 af[MT], bfr[NT];
            #pragma unroll
            for (int i = 0; i < MT; ++i) {
                const int rowA = wr * (TM / 2) + i * 16 + l16;
                af[i] = *(const short8*)&As[rowA][((quad + rowA) & 3) * 8];
            }
            #pragma unroll
            for (int j2 = 0; j2 < NT; ++j2) {
                const int rowB = wc * (TN / 2) + j2 * 16 + l16;
                bfr[j2] = *(const short8*)&Bs[rowB][((quad + rowB) & 3) * 8];
            }
            #pragma unroll
            for (int i = 0; i < MT; ++i)
                #pragma unroll
                for (int j2 = 0; j2 < NT; ++j2)
                    acc[i][j2] = __builtin_amdgcn_mfma_f32_16x16x32_bf16(
                        af[i], bfr[j2], acc[i][j2], 0, 0, 0);
            __syncthreads();
        }
    }

    float s = 0.f, ss = 0.f;
    #pragma unroll
    for (int i = 0; i < MT; ++i) {
        #pragma unroll
        for (int j2 = 0; j2 < NT; ++j2) {
            const long row = m0 + wr * (TM / 2) + i * 16 + quad * 4;
            const long col = n0 + wc * (TN / 2) + j2 * 16 + l16;
            #pragma unroll
            for (int rr = 0; rr < 4; ++rr) {
                const float v = alpha * acc[i][j2][rr];
                if constexpr (sizeof(TC) == 4)
                    C[(row + rr) * ldc + col] = v;
                else
                    C[(row + rr) * ldc + col] = f2bf(v);
                if constexpr (STATS) {
                    if (row + rr < KVD) { s += v; ss += v * v; }  // pad cols are exact 0
                }
            }
        }
    }
    if constexpr (STATS) {
        float* red = (float*)&As[0][0];     // 8 KB >= 512 floats (TM=128 only)
        red[tid] = s; red[256 + tid] = ss;
        __syncthreads();
        for (int o = 128; o > 0; o >>= 1) {
            if (tid < o) { red[tid] += red[tid + o]; red[256 + tid] += red[256 + tid + o]; }
            __syncthreads();
        }
        if (tid == 0) {
            const int bidx = (m0 >= 896) ? 0 : (m0 >= 768) ? 1 : (m0 >= 512) ? 2 : 3;
            atomicAdd(&statsAcc[((long)z * 4 + bidx) * 2],     red[0]);
            atomicAdd(&statsAcc[((long)z * 4 + bidx) * 2 + 1], red[256]);
        }
    }
}

// ---- softmax over real 960 cols; stats finalize inlined (reads atomic sums).
// grid (ECAT, Z), block 256; branch resolved from concat row.
__global__ void softmax_kernel(const float* __restrict__ S,
                               short* __restrict__ Sa,
                               const float* __restrict__ acc)
{
    const int row = blockIdx.x;          // 0..1023 concat rows (>=960 = pad)
    const int y   = blockIdx.y;
    const int t   = threadIdx.x;
    short* orow = Sa + ((long)y * ECAT + row) * KVP;
    if (row >= KVD) {                    // zero pad row (clean B-operand for Ch)
        *(short4e*)(orow + 4 * t) = (short4e){0, 0, 0, 0};
        return;
    }
    const int bidx = (row >= 896) ? 0 : (row >= 768) ? 1 : (row >= 512) ? 2 : 3;
    const int dftab[4] = {64, 128, 256, 512};
    const float sum0 = acc[((long)y * 4 + bidx) * 2];
    const float ssq0 = acc[((long)y * 4 + bidx) * 2 + 1];
    const float n    = (float)(dftab[bidx] * KVD);
    const float mean = sum0 / n;
    const float rstd = rsqrtf(ssq0 / n - mean * mean + EPS);
    const float* srow = S + ((long)y * ECAT + row) * KVP;

    const bool real = (t < KVD / 4);     // threads 0..239 hold real cols (4 each)
    float x[4];
    float mx = -1e30f;
    if (real) {
        const float4 v = *(const float4*)(srow + 4 * t);
        x[0] = (v.x - mean) * rstd; x[1] = (v.y - mean) * rstd;
        x[2] = (v.z - mean) * rstd; x[3] = (v.w - mean) * rstd;
        mx = fmaxf(fmaxf(x[0], x[1]), fmaxf(x[2], x[3]));
    }
    __shared__ float red[256];
    red[t] = mx; __syncthreads();
    for (int o = 128; o > 0; o >>= 1) {
        if (t < o) red[t] = fmaxf(red[t], red[t + o]);
        __syncthreads();
    }
    mx = red[0];
    __syncthreads();

    float e[4] = {0.f, 0.f, 0.f, 0.f};
    float sum = 0.f;
    if (real) {
        e[0] = __expf(x[0] - mx); e[1] = __expf(x[1] - mx);
        e[2] = __expf(x[2] - mx); e[3] = __expf(x[3] - mx);
        sum = e[0] + e[1] + e[2] + e[3];
    }
    red[t] = sum; __syncthreads();
    for (int o = 128; o > 0; o >>= 1) {
        if (t < o) red[t] += red[t + o];
        __syncthreads();
    }
    const float inv = 1.0f / red[0];
    short4e o4;
    o4[0] = f2bf(e[0] * inv); o4[1] = f2bf(e[1] * inv);
    o4[2] = f2bf(e[2] * inv); o4[3] = f2bf(e[3] * inv);
    *(short4e*)(orow + 4 * t) = o4;
}

// ---------------------------------------------------------------------------
extern "C" void kernel_launch(void* const* d_in, const int* in_sizes, int n_in,
                              void* d_out, int out_size, void* d_ws, size_t ws_size,
                              hipStream_t stream)
{
    (void)in_sizes; (void)n_in; (void)out_size;
    const float* emb[4]  = {(const float*)d_in[0], (const float*)d_in[1],
                            (const float*)d_in[2], (const float*)d_in[3]};
    const float* emb_all = (const float*)d_in[4];
    const float* WQ[4]   = {(const float*)d_in[5], (const float*)d_in[6],
                            (const float*)d_in[7], (const float*)d_in[8]};
    const float* WK      = (const float*)d_in[9];
    const float* WV      = (const float*)d_in[10];
    const float* WO[4]   = {(const float*)d_in[11], (const float*)d_in[12],
                            (const float*)d_in[13], (const float*)d_in[14]};
    float* out = (float*)d_out;

    const int dfs[4]    = {64, 128, 256, 512};
    const int rowoff[4] = {896, 768, 512, 0};   // concat offsets (tile-aligned)
    const long N = NSEQ;

    // ---- workspace budget
    const long eAll = (long)BATCH * N * KVD;
    const long eWKp = (long)HH * KVP * KVD;
    long preBytes = eAll * 2 + 2 * eWKp * 2;
    for (int br = 0; br < 4; ++br)
        preBytes += ((long)BATCH * N * dfs[br] + (long)HH * dfs[br] * dfs[br]
                    + (long)dfs[br] * dfs[br]) * 2;
    const long perG = (long)HH * KVP * N * 2      // KT
                    + (long)HH * N * KVP * 2      // V
                    + (long)HH * ECAT * N * 2     // Qcat
                    + (long)HH * ECAT * KVP * 4   // Scat (Chcat aliases this)
                    + (long)HH * ECAT * KVP * 2;  // Sacat
    int G = 8;
    while (G > 1 && preBytes + (long)G * perG + 65536 > (long)ws_size) G >>= 1;

    // ---- carve workspace
    char* p = (char*)d_ws;
    short* embAllp = (short*)p; p += eAll * 2;
    short* embp[4]; short* WQp[4]; short* WOp[4];
    for (int br = 0; br < 4; ++br) { embp[br] = (short*)p; p += (long)BATCH * N * dfs[br] * 2; }
    for (int br = 0; br < 4; ++br) { WQp[br]  = (short*)p; p += (long)HH * dfs[br] * dfs[br] * 2; }
    short* WKp = (short*)p; p += eWKp * 2;
    short* WVp = (short*)p; p += eWKp * 2;
    for (int br = 0; br < 4; ++br) { WOp[br]  = (short*)p; p += (long)dfs[br] * dfs[br] * 2; }
    short* KTb = (short*)p; p += (long)G * HH * KVP * N * 2;
    short* Vb  = (short*)p; p += (long)G * HH * N * KVP * 2;
    short* Qb  = (short*)p; p += (long)G * HH * ECAT * N * 2;    // Qcat
    float* Sb  = (float*)p; p += (long)G * HH * ECAT * KVP * 4;  // Scat
    short* Sab = (short*)p; p += (long)G * HH * ECAT * KVP * 2;  // Sacat
    float* statsAcc = (float*)p; p += (long)BATCH * HH * 4 * 2 * 4;  // all b0 slices
    short* Chb = (short*)Sb;   // Chcat aliases Scat (Scat fully consumed by softmax)

    // ---- ONE convert launch: 13 plain segments + 2 padded-W segments
    {
        ConvJobs J;
        long cum = 0; int sg = 0;
        auto addJob = [&](const float* src, short* dst, long nunits, int ty) {
            J.src[sg] = src; J.dst[sg] = dst; J.cum[sg] = cum; J.type[sg] = ty;
            cum += nunits; ++sg;
        };
        addJob(emb_all, embAllp, eAll / 8, 0);
        for (int br = 0; br < 4; ++br) addJob(emb[br], embp[br], (long)BATCH * N * dfs[br] / 8, 0);
        for (int br = 0; br < 4; ++br) addJob(WQ[br], WQp[br], (long)HH * dfs[br] * dfs[br] / 8, 0);
        for (int br = 0; br < 4; ++br) addJob(WO[br], WOp[br], (long)dfs[br] * dfs[br] / 8, 0);
        addJob(WK, WKp, (long)HH * KVP * (KVD / 8), 1);
        addJob(WV, WVp, (long)HH * KVP * (KVD / 8), 1);
        J.cum[15] = cum;
        J.statsAcc = statsAcc;
        J.nAcc = BATCH * HH * 4 * 2;    // 256 — zero every b0 slice up front
        conv_all_kernel<<<dim3((unsigned)((cum + 255) / 256)), dim3(256), 0, stream>>>(J);
    }

    const float scale = 1.0f / sqrtf((float)KVD);
    long outBase[4];
    {
        long acc = 0;
        for (int br = 0; br < 4; ++br) { outBase[br] = acc; acc += (long)BATCH * N * dfs[br]; }
    }

    const dim3 blk(256);
    int it = 0;
    for (int b0 = 0; b0 < BATCH; b0 += G, ++it) {
        const int Z = G * HH;
        const short* embA = embAllp + (long)b0 * N * KVD;
        float* accIt = statsAcc + (long)it * Z * 4 * 2;

        // ---- proj mega-launch: KT + V + Q(4 branches), one job table ----------
        {
            GemmJobs J; int nj = 0; int base = 0;
            auto add = [&](const short* A, const short* B, void* C, float alpha,
                           int lda, int ldb, int ldc, int K, int inner,
                           long sA, long sB, long zAh, long zAg, long zBh, long zBg,
                           long zCh, long zCg, int splitH, int gx, int gy, int Zj, int cfg,
                           int nblk) {
                GemmJob& q = J.j[nj];
                q.A = A; q.B = B; q.C = C; q.alpha = alpha;
                q.lda = lda; q.ldb = ldb; q.ldc = ldc; q.K = K; q.inner = inner;
                q.sA = sA; q.sB = sB; q.zAh = zAh; q.zAg = zAg; q.zBh = zBh; q.zBg = zBg;
                q.zCh = zCh; q.zCg = zCg; q.splitH = splitH; q.gx = gx; q.gy = gy;
                q.Z = Zj; q.cfg = cfg; q.blkBase = base;
                base += nblk; ++nj;
            };
            // KT[g][h][j(1024)][n] = sum_k WKp[h][j][k] embA[g][n][k]
            add(WKp, embA, KTb, 1.0f, KVD, KVD, (int)N, KVD, 1,
                0, 0, (long)KVP * KVD, 0, 0, (long)N * KVD,
                (long)KVP * N, (long)HH * KVP * N, 1, 8, 8, Z, 0, 8 * 8 * Z);
            // V[g][h][n][j(1024)] = sum_k embA[g][n][k] WVp[h][j][k]
            add(embA, WVp, Vb, 1.0f, KVD, KVD, KVP, KVD, 1,
                0, 0, 0, (long)N * KVD, (long)KVP * KVD, 0,
                (long)N * KVP, (long)HH * N * KVP, 1, 8, 8, Z, 0, 8 * 8 * Z);
            // Q branches -> concat rows of Qcat[g][h][ECAT][N]
            for (int br = 3; br >= 0; --br) {       // big df first
                const int df = dfs[br];
                const short* embB = embp[br] + (long)b0 * N * df;
                short* Qdst = Qb + (long)rowoff[br] * N;
                if (df >= 128)
                    add(WQp[br], embB, Qdst, 1.0f, df, df, (int)N, df, 1,
                        0, 0, (long)df * df, 0, 0, (long)N * df,
                        (long)ECAT * N, (long)HH * ECAT * N, 1, 8, df / 128, Z, 0,
                        8 * (df / 128) * Z);
                else
                    add(WQp[br], embB, Qdst, 1.0f, df, df, (int)N, df, 1,
                        0, 0, (long)df * df, 0, 0, (long)N * df,
                        (long)ECAT * N, (long)HH * ECAT * N, 1, 8, 1, Z, 2,
                        8 * 1 * Z);
            }
            J.njobs = nj;
            mfma_jt<short><<<dim3(base), blk, 0, stream>>>(J);
        }

        // S merged: S[g][h][e_cat][j] = scale * sum_n Qcat[e][n] KT[j][n]
        //   M=ECAT, Nc=KVP, K=N; fused per-branch stats via atomics (STATS=1)
        mfma_nt<128, 128, float, 1><<<dim3(8 * 8 * Z), blk, 0, stream>>>(
            Qb, KTb, Sb, (int)N, (int)N, KVP, (int)N, scale, 1, 0, 0,
            (long)ECAT * N, (long)HH * ECAT * N,
            (long)KVP * N, (long)HH * KVP * N,
            (long)ECAT * KVP, (long)HH * ECAT * KVP, 1, 8, 8, accIt);

        // softmax (stats finalize inlined)
        softmax_kernel<<<dim3(ECAT, Z), dim3(256), 0, stream>>>(Sb, Sab, accIt);

        // Ch merged: Ch[g][h][n][e_cat] = sum_j V[n][j] Sa[e_cat][j]
        mfma_nt<128, 128, short><<<dim3(8 * 8 * Z), blk, 0, stream>>>(
            Vb, Sab, Chb, KVP, KVP, ECAT, KVP, 1.0f, 1, 0, 0,
            (long)N * KVP, (long)HH * N * KVP,
            (long)ECAT * KVP, (long)HH * ECAT * KVP,
            (long)N * ECAT, (long)HH * N * ECAT, 1, 8, 8, nullptr);

        // ---- O mega-launch: 4 branches, one job table -------------------------
        {
            GemmJobs J; int nj = 0; int base = 0;
            for (int br = 3; br >= 0; --br) {       // big df first
                const int df = dfs[br];
                const short* Asrc = Chb + rowoff[br];
                float* Cout = out + outBase[br] + (long)b0 * N * df;
                GemmJob& q = J.j[nj];
                q.A = Asrc; q.B = WOp[br]; q.C = Cout; q.alpha = 1.0f / HH;
                q.lda = ECAT; q.ldb = df; q.ldc = df; q.K = df; q.inner = HH;
                q.sA = (long)N * ECAT; q.sB = 0;
                q.zAh = 0; q.zAg = (long)HH * N * ECAT; q.zBh = 0; q.zBg = 0;
                q.zCh = 0; q.zCg = (long)N * df;
                q.splitH = 0; q.Z = G; q.gy = 8;
                if (df >= 128) { q.cfg = 0; q.gx = df / 128; }
                else           { q.cfg = 1; q.gx = 1;        }
                q.blkBase = base;
                base += q.gx * q.gy * G;
                ++nj;
            }
            J.njobs = nj;
            mfma_jt<float><<<dim3(base), blk, 0, stream>>>(J);
        }
    }
}

// Round 3
// 645.519 us; speedup vs baseline: 1.7112x; 1.0856x over previous
//
#include <hip/hip_runtime.h>
#include <hip/hip_bf16.h>
#include <math.h>

#define HH    4
#define NSEQ  1024
#define KVD   960    // true KV dim
#define KVP   1024   // padded KV dim (zero pad) so every tile dim is 128-divisible
#define BATCH 8
#define ECAT  1024   // concat of branch channel dims (960 real, 64 pad rows)

static constexpr float EPS = 1e-5f;

typedef __attribute__((ext_vector_type(8))) short short8;   // 8 bf16
typedef __attribute__((ext_vector_type(4))) short short4e;  // 4 bf16
typedef __attribute__((ext_vector_type(4))) float f32x4;    // MFMA C/D frag

__device__ __forceinline__ short f2bf(float x) {
    union { __hip_bfloat16 h; short s; } u;
    u.h = __float2bfloat16(x);
    return u.s;
}
__device__ __forceinline__ short8 cvt8(const float* __restrict__ g) {
    const float4 a = *(const float4*)g;
    const float4 b = *(const float4*)(g + 4);
    short8 t;
    t[0] = f2bf(a.x); t[1] = f2bf(a.y); t[2] = f2bf(a.z); t[3] = f2bf(a.w);
    t[4] = f2bf(b.x); t[5] = f2bf(b.y); t[6] = f2bf(b.z); t[7] = f2bf(b.w);
    return t;
}

// ---- one-time input converts: 15 segments (13 plain + 2 padded-W) in ONE launch
struct ConvJobs {
    const float* src[15];
    short*       dst[15];
    long         cum[16];    // cum[i] = start (short8 units) of job i; cum[15] = total
    int          type[15];   // 0 = plain copy, 1 = padded WK/WV layout
    float*       statsAcc;   // zero-init side effect (block 0)
    int          nAcc;
};

__global__ void conv_all_kernel(ConvJobs J)
{
    if (blockIdx.x == 0 && threadIdx.x < (unsigned)J.nAcc)
        J.statsAcc[threadIdx.x] = 0.f;
    const long u = (long)blockIdx.x * 256 + threadIdx.x;
    if (u >= J.cum[15]) return;
    int sg = 0;
    while (u >= J.cum[sg + 1]) ++sg;
    const long l = u - J.cum[sg];
    if (J.type[sg] == 0) {
        *(short8*)(J.dst[sg] + l * 8) = cvt8(J.src[sg] + l * 8);
    } else {
        // [H][960][960] fp32 -> [H][1024][960] bf16, rows 960..1023 zeroed
        const int cpr = KVD / 8;                              // 120
        const int c8  = (int)(l % cpr) * 8;
        const int row = (int)((l / cpr) % KVP);
        const int h   = (int)(l / ((long)cpr * KVP));
        short8 t = (short8){0,0,0,0,0,0,0,0};
        if (row < KVD) t = cvt8(J.src[sg] + ((long)h * KVD + row) * KVD + c8);
        *(short8*)(J.dst[sg] + ((long)h * KVP + row) * KVD + c8) = t;
    }
}

// ---- legacy async LDS staging: ROWS x 32 bf16, 64B rows, chunk-XOR swizzle.
template<int ROWS>
__device__ __forceinline__ void stage_async(short (*dst)[32], const short* __restrict__ src,
                                            int ld, int w, int lane)
{
    #pragma unroll
    for (int p = 0; p < ROWS / 64; ++p) {
        const int rbase = p * 64 + w * 16;
        const int row   = rbase + (lane >> 2);
        const int c16l  = ((lane & 3) - row) & 3;   // logical chunk landing at this slot
        const short* g  = src + (long)row * ld + c16l * 8;
        __builtin_amdgcn_global_load_lds(
            (const __attribute__((address_space(1))) void*)g,
            (__attribute__((address_space(3))) void*)&dst[rbase][0],
            16, 0, 0);
    }
}

// ---------------------------------------------------------------------------
// Job descriptor shared by the legacy 128^2 job-table kernel and the new
// 256^2 8-phase kernel.
// ---------------------------------------------------------------------------
struct GemmJob {
    const short* A; const short* B; void* C;
    float alpha;
    int lda, ldb, ldc, K, inner, gx, gy, Z, splitH, cfg, blkBase, pad0;
    long sA, sB, zAh, zAg, zBh, zBg, zCh, zCg;
};
struct GemmJobs { GemmJob j[8]; int njobs; };

// ---- legacy 128^2 GEMM body (verified): C = alpha * sum_ib A[M,K] @ B[Nc,K]^T
template<int TM, int TN, typename TC>
__device__ __forceinline__ void gemm_body(const GemmJob& job, int lb,
                                          short (*As)[32], short (*Bs)[32])
{
    constexpr int MT = TM / 32;
    constexpr int NT = TN / 32;
    const short* A = job.A;
    const short* B = job.B;
    TC* C = (TC*)job.C;
    const int bps = job.gx * job.gy;
    const int Z   = job.Z;
    int z, r;
    if ((Z & 7) == 0) {
        const int xcd = lb & 7;
        const int j   = lb >> 3;
        const int spx = Z >> 3;
        z = xcd * spx + j / bps;
        r = j % bps;
    } else {
        z = lb / bps;
        r = lb % bps;
    }
    const int x = r % job.gx, y = r / job.gx;
    int h, g;
    if (job.splitH) { h = z & (HH - 1); g = z >> 2; }
    else            { h = 0;            g = z;      }
    A += (long)h * job.zAh + (long)g * job.zAg;
    B += (long)h * job.zBh + (long)g * job.zBg;
    C += (long)h * job.zCh + (long)g * job.zCg;

    const int tid  = threadIdx.x;
    const int lane = tid & 63;
    const int w    = tid >> 6;
    const int wr   = w >> 1;
    const int wc   = w & 1;
    const int quad = lane >> 4;
    const int l16  = lane & 15;
    const long m0  = (long)y * TM;
    const long n0  = (long)x * TN;

    f32x4 acc[MT][NT];
    #pragma unroll
    for (int i = 0; i < MT; ++i)
        #pragma unroll
        for (int j2 = 0; j2 < NT; ++j2)
            acc[i][j2] = (f32x4){0.f, 0.f, 0.f, 0.f};

    for (int ib = 0; ib < job.inner; ++ib) {
        const short* Ab = A + (long)ib * job.sA + m0 * job.lda;
        const short* Bb = B + (long)ib * job.sB + n0 * job.ldb;
        for (int k0 = 0; k0 < job.K; k0 += 32) {
            stage_async<TM>(As, Ab + k0, job.lda, w, lane);
            stage_async<TN>(Bs, Bb + k0, job.ldb, w, lane);
            __syncthreads();
            short8 af[MT], bfr[NT];
            #pragma unroll
            for (int i = 0; i < MT; ++i) {
                const int rowA = wr * (TM / 2) + i * 16 + l16;
                af[i] = *(const short8*)&As[rowA][((quad + rowA) & 3) * 8];
            }
            #pragma unroll
            for (int j2 = 0; j2 < NT; ++j2) {
                const int rowB = wc * (TN / 2) + j2 * 16 + l16;
                bfr[j2] = *(const short8*)&Bs[rowB][((quad + rowB) & 3) * 8];
            }
            #pragma unroll
            for (int i = 0; i < MT; ++i)
                #pragma unroll
                for (int j2 = 0; j2 < NT; ++j2)
                    acc[i][j2] = __builtin_amdgcn_mfma_f32_16x16x32_bf16(
                        af[i], bfr[j2], acc[i][j2], 0, 0, 0);
            __syncthreads();
        }
    }

    #pragma unroll
    for (int i = 0; i < MT; ++i) {
        #pragma unroll
        for (int j2 = 0; j2 < NT; ++j2) {
            const long row = m0 + wr * (TM / 2) + i * 16 + quad * 4;
            const long col = n0 + wc * (TN / 2) + j2 * 16 + l16;
            #pragma unroll
            for (int rr = 0; rr < 4; ++rr) {
                const float v = job.alpha * acc[i][j2][rr];
                if constexpr (sizeof(TC) == 4)
                    C[(row + rr) * job.ldc + col] = v;
                else
                    C[(row + rr) * job.ldc + col] = f2bf(v);
            }
        }
    }
}

template<typename TC>
__global__ __launch_bounds__(256) void mfma_jt(GemmJobs J)
{
    __shared__ short As[128][32];
    __shared__ short Bs[128][32];
    const int bid = blockIdx.x;
    int ji = 0;
    while (ji + 1 < J.njobs && bid >= J.j[ji + 1].blkBase) ++ji;
    const GemmJob& job = J.j[ji];
    const int lb = bid - job.blkBase;
    switch (job.cfg) {
        case 0: gemm_body<128, 128, TC>(job, lb, As, Bs); break;
        case 1: gemm_body<128,  64, TC>(job, lb, As, Bs); break;
        default: gemm_body<64, 128, TC>(job, lb, As, Bs); break;
    }
}

// ---------------------------------------------------------------------------
// NEW: 256^2-tile, BK=64, 8-wave, 8-phase bf16 NT GEMM with counted vmcnt.
// C[M,Nc] = alpha * A[M,K] @ B[Nc,K]^T, M=Nc=1024 (4x4 tiles/slice), K%64==0.
// LDS: AT/BT = 2 bufs x 2 halves x [128][64] bf16 = 128 KiB total.
// Swizzle: row r's logical 16B chunk c stored at physical chunk (c+r)&7
// (2-way bank aliasing on ds_read_b128 = free). global_load_lds keeps the LDS
// dest linear; the per-lane GLOBAL source address is pre-swizzled [m104/m173].
// Schedule per K-tile t (buf=t&1): 4 phases = C-quadrants (a,b) in order
// (0,0),(0,1),(1,0),(1,1); phase stages one future half-tile:
//   ph1:(t+1)A1  ph2:(t+1)B1  ph3:(t+2)A0  ph4:(t+2)B0, then vmcnt(4)
// so tile t+1 is fully staged+published at the tile boundary while tile t+2's
// A0/B0 stay in flight across the barrier (never vmcnt(0) in steady state).
// Overwrite safety: a region is re-staged only after its last reader phase's
// lgkmcnt(0)-drained MFMAs and a subsequent s_barrier.
// ---------------------------------------------------------------------------
__device__ __forceinline__ void stage_half8(short* ldsb, const short* src,
                                            int ld, int w, int lane)
{
    #pragma unroll
    for (int i = 0; i < 2; ++i) {
        const int o16 = i * 512 + w * 64 + lane;   // 16B-unit index 0..1023
        const int row = o16 >> 3;                  // 8 chunks per 128B row
        const int pc  = o16 & 7;                   // physical chunk
        const int lc  = (pc - row) & 7;            // logical chunk landing here
        __builtin_amdgcn_global_load_lds(
            (const __attribute__((address_space(1))) void*)(src + (long)row * ld + lc * 8),
            (__attribute__((address_space(3))) void*)(ldsb + (i * 512 + w * 64) * 8),
            16, 0, 0);
    }
}

#define PH(aa, bb, ...) do {                                                     \
    short8 paf_[4][2], pbf_[2][2];                                               \
    _Pragma("unroll")                                                            \
    for (int mi2_ = 0; mi2_ < 4; ++mi2_) {                                       \
        const int r_ = mi2_ * 32 + wm * 16 + l16;                                \
        _Pragma("unroll")                                                        \
        for (int ks_ = 0; ks_ < 2; ++ks_) {                                      \
            const int c_ = ks_ * 4 + quad;                                       \
            paf_[mi2_][ks_] = *(const short8*)&AT[q][aa][r_][((c_ + r_) & 7) * 8]; \
        }                                                                        \
    }                                                                            \
    _Pragma("unroll")                                                            \
    for (int nj2_ = 0; nj2_ < 2; ++nj2_) {                                       \
        const int r_ = nj2_ * 64 + wn * 16 + l16;                                \
        _Pragma("unroll")                                                        \
        for (int ks_ = 0; ks_ < 2; ++ks_) {                                      \
            const int c_ = ks_ * 4 + quad;                                       \
            pbf_[nj2_][ks_] = *(const short8*)&BT[q][bb][r_][((c_ + r_) & 7) * 8]; \
        }                                                                        \
    }                                                                            \
    __VA_ARGS__;                                                                 \
    __builtin_amdgcn_s_barrier();                                                \
    asm volatile("s_waitcnt lgkmcnt(0)" ::: "memory");                           \
    __builtin_amdgcn_sched_barrier(0);                                           \
    __builtin_amdgcn_s_setprio(1);                                               \
    _Pragma("unroll")                                                            \
    for (int mi2_ = 0; mi2_ < 4; ++mi2_) {                                       \
        _Pragma("unroll")                                                        \
        for (int nj2_ = 0; nj2_ < 2; ++nj2_) {                                   \
            acc[(aa)*4 + mi2_][(bb)*2 + nj2_] =                                  \
                __builtin_amdgcn_mfma_f32_16x16x32_bf16(                         \
                    paf_[mi2_][0], pbf_[nj2_][0],                                \
                    acc[(aa)*4 + mi2_][(bb)*2 + nj2_], 0, 0, 0);                 \
            acc[(aa)*4 + mi2_][(bb)*2 + nj2_] =                                  \
                __builtin_amdgcn_mfma_f32_16x16x32_bf16(                         \
                    paf_[mi2_][1], pbf_[nj2_][1],                                \
                    acc[(aa)*4 + mi2_][(bb)*2 + nj2_], 0, 0, 0);                 \
        }                                                                        \
    }                                                                            \
    __builtin_amdgcn_s_setprio(0);                                               \
    __builtin_amdgcn_s_barrier();                                                \
} while (0)

template<typename TC, int STATS>
__global__ __launch_bounds__(512) void mfma8(GemmJobs J, float* __restrict__ statsAcc)
{
    __shared__ short AT[2][2][128][64];
    __shared__ short BT[2][2][128][64];

    const int bid = blockIdx.x;
    int ji = 0;
    while (ji + 1 < J.njobs && bid >= J.j[ji + 1].blkBase) ++ji;
    const GemmJob& job = J.j[ji];
    const int lb = bid - job.blkBase;
    const int Z  = job.Z;
    int z, r;
    if ((Z & 7) == 0) {
        const int xcd = lb & 7;
        const int jj  = lb >> 3;
        const int spx = Z >> 3;
        z = xcd * spx + jj / 16;
        r = jj % 16;
    } else {
        z = lb / 16;
        r = lb % 16;
    }
    const int x = r & 3, y = r >> 2;
    int h, g;
    if (job.splitH) { h = z & (HH - 1); g = z >> 2; }
    else            { h = 0;            g = z;      }
    const int lda = job.lda, ldb = job.ldb, ldc = job.ldc;
    const short* A = job.A + (long)h * job.zAh + (long)g * job.zAg + (long)(y * 256) * lda;
    const short* B = job.B + (long)h * job.zBh + (long)g * job.zBg + (long)(x * 256) * ldb;
    TC* C = (TC*)job.C + (long)h * job.zCh + (long)g * job.zCg;
    const int NT = job.K >> 6;

    const int tid  = threadIdx.x;
    const int lane = tid & 63;
    const int w    = tid >> 6;
    const int wm   = w >> 2;        // 0..1
    const int wn   = w & 3;         // 0..3
    const int quad = lane >> 4;
    const int l16  = lane & 15;

    f32x4 acc[8][4];
    #pragma unroll
    for (int i = 0; i < 8; ++i)
        #pragma unroll
        for (int j2 = 0; j2 < 4; ++j2)
            acc[i][j2] = (f32x4){0.f, 0.f, 0.f, 0.f};

    // staging lambdas: half hh of K-tile t into buf t&1
    auto SA = [&](int t, int hh) {
        stage_half8(&AT[t & 1][hh][0][0], A + (long)(hh * 128) * lda + t * 64, lda, w, lane);
    };
    auto SB = [&](int t, int hh) {
        stage_half8(&BT[t & 1][hh][0][0], B + (long)(hh * 128) * ldb + t * 64, ldb, w, lane);
    };

    // prologue: tile0 all 4 halves + tile1 A0/B0; drain tile0, keep tile1 in flight
    SA(0, 0); SA(0, 1); SB(0, 0); SB(0, 1);
    if (1 < NT) { SA(1, 0); SB(1, 0); }
    if (1 < NT) asm volatile("s_waitcnt vmcnt(4)" ::: "memory");
    else        asm volatile("s_waitcnt vmcnt(0)" ::: "memory");
    __builtin_amdgcn_s_barrier();

    for (int t = 0; t < NT; ++t) {
        const int q = t & 1;
        PH(0, 0, { if (t + 1 < NT) SA(t + 1, 1); });
        PH(0, 1, { if (t + 1 < NT) SB(t + 1, 1); });
        PH(1, 0, { if (t + 2 < NT) SA(t + 2, 0); });
        PH(1, 1, {
            if (t + 2 < NT) {
                SB(t + 2, 0);
                asm volatile("s_waitcnt vmcnt(4)" ::: "memory");
            } else {
                asm volatile("s_waitcnt vmcnt(0)" ::: "memory");
            }
        });
    }

    // epilogue: C/D layout col=lane&15, row=(lane>>4)*4+reg [m89-verified]
    float s0 = 0.f, ss0 = 0.f, s1 = 0.f, ss1 = 0.f;   // buckets: rows<896, rows 896..959
    #pragma unroll
    for (int mi = 0; mi < 8; ++mi) {
        #pragma unroll
        for (int nj = 0; nj < 4; ++nj) {
            const long row = (long)y * 256 + mi * 32 + wm * 16 + quad * 4;
            const long col = (long)x * 256 + nj * 64 + wn * 16 + l16;
            #pragma unroll
            for (int rr = 0; rr < 4; ++rr) {
                const float v = job.alpha * acc[mi][nj][rr];
                if constexpr (sizeof(TC) == 4)
                    C[(row + rr) * ldc + col] = v;
                else
                    C[(row + rr) * ldc + col] = f2bf(v);
                if constexpr (STATS) {
                    const long gr = row + rr;
                    if (gr < 896)          { s0 += v; ss0 += v * v; }
                    else if (gr < KVD)     { s1 += v; ss1 += v * v; }
                }
            }
        }
    }
    if constexpr (STATS) {
        __syncthreads();
        float* red = (float*)&AT[0][0][0][0];   // 4 x 512 floats, LDS free now
        red[tid] = s0; red[512 + tid] = ss0; red[1024 + tid] = s1; red[1536 + tid] = ss1;
        __syncthreads();
        for (int o = 256; o > 0; o >>= 1) {
            if (tid < o) {
                red[tid]        += red[tid + o];
                red[512 + tid]  += red[512 + tid + o];
                red[1024 + tid] += red[1024 + tid + o];
                red[1536 + tid] += red[1536 + tid + o];
            }
            __syncthreads();
        }
        if (tid == 0) {
            // bucket A: this tile's rows below 896 -> branch by tile row base
            const int m0g = y * 256;
            const int bA = (m0g >= 768) ? 1 : (m0g >= 512) ? 2 : 3;
            atomicAdd(&statsAcc[((long)z * 4 + bA) * 2],     red[0]);
            atomicAdd(&statsAcc[((long)z * 4 + bA) * 2 + 1], red[512]);
            if (y == 3) {   // rows 896..959 -> branch 0 (df=64)
                atomicAdd(&statsAcc[((long)z * 4 + 0) * 2],     red[1024]);
                atomicAdd(&statsAcc[((long)z * 4 + 0) * 2 + 1], red[1536]);
            }
        }
    }
}

// ---- softmax over real 960 cols; stats finalize inlined (reads atomic sums).
// grid (ECAT, Z), block 256; branch resolved from concat row.
__global__ void softmax_kernel(const float* __restrict__ S,
                               short* __restrict__ Sa,
                               const float* __restrict__ acc)
{
    const int row = blockIdx.x;          // 0..1023 concat rows (>=960 = pad)
    const int y   = blockIdx.y;
    const int t   = threadIdx.x;
    short* orow = Sa + ((long)y * ECAT + row) * KVP;
    if (row >= KVD) {                    // zero pad row (clean B-operand for Ch)
        *(short4e*)(orow + 4 * t) = (short4e){0, 0, 0, 0};
        return;
    }
    const int bidx = (row >= 896) ? 0 : (row >= 768) ? 1 : (row >= 512) ? 2 : 3;
    const int dftab[4] = {64, 128, 256, 512};
    const float sum0 = acc[((long)y * 4 + bidx) * 2];
    const float ssq0 = acc[((long)y * 4 + bidx) * 2 + 1];
    const float n    = (float)(dftab[bidx] * KVD);
    const float mean = sum0 / n;
    const float rstd = rsqrtf(ssq0 / n - mean * mean + EPS);
    const float* srow = S + ((long)y * ECAT + row) * KVP;

    const bool real = (t < KVD / 4);     // threads 0..239 hold real cols (4 each)
    float x[4];
    float mx = -1e30f;
    if (real) {
        const float4 v = *(const float4*)(srow + 4 * t);
        x[0] = (v.x - mean) * rstd; x[1] = (v.y - mean) * rstd;
        x[2] = (v.z - mean) * rstd; x[3] = (v.w - mean) * rstd;
        mx = fmaxf(fmaxf(x[0], x[1]), fmaxf(x[2], x[3]));
    }
    __shared__ float red[256];
    red[t] = mx; __syncthreads();
    for (int o = 128; o > 0; o >>= 1) {
        if (t < o) red[t] = fmaxf(red[t], red[t + o]);
        __syncthreads();
    }
    mx = red[0];
    __syncthreads();

    float e[4] = {0.f, 0.f, 0.f, 0.f};
    float sum = 0.f;
    if (real) {
        e[0] = __expf(x[0] - mx); e[1] = __expf(x[1] - mx);
        e[2] = __expf(x[2] - mx); e[3] = __expf(x[3] - mx);
        sum = e[0] + e[1] + e[2] + e[3];
    }
    red[t] = sum; __syncthreads();
    for (int o = 128; o > 0; o >>= 1) {
        if (t < o) red[t] += red[t + o];
        __syncthreads();
    }
    const float inv = 1.0f / red[0];
    short4e o4;
    o4[0] = f2bf(e[0] * inv); o4[1] = f2bf(e[1] * inv);
    o4[2] = f2bf(e[2] * inv); o4[3] = f2bf(e[3] * inv);
    *(short4e*)(orow + 4 * t) = o4;
}

// ---------------------------------------------------------------------------
extern "C" void kernel_launch(void* const* d_in, const int* in_sizes, int n_in,
                              void* d_out, int out_size, void* d_ws, size_t ws_size,
                              hipStream_t stream)
{
    (void)in_sizes; (void)n_in; (void)out_size;
    const float* emb[4]  = {(const float*)d_in[0], (const float*)d_in[1],
                            (const float*)d_in[2], (const float*)d_in[3]};
    const float* emb_all = (const float*)d_in[4];
    const float* WQ[4]   = {(const float*)d_in[5], (const float*)d_in[6],
                            (const float*)d_in[7], (const float*)d_in[8]};
    const float* WK      = (const float*)d_in[9];
    const float* WV      = (const float*)d_in[10];
    const float* WO[4]   = {(const float*)d_in[11], (const float*)d_in[12],
                            (const float*)d_in[13], (const float*)d_in[14]};
    float* out = (float*)d_out;

    const int dfs[4]    = {64, 128, 256, 512};
    const int rowoff[4] = {896, 768, 512, 0};   // concat offsets (tile-aligned)
    const long N = NSEQ;

    // ---- workspace budget (Sacat aliases KT+Qcat: both dead before softmax)
    const long eAll = (long)BATCH * N * KVD;
    const long eWKp = (long)HH * KVP * KVD;
    long preBytes = eAll * 2 + 2 * eWKp * 2;
    for (int br = 0; br < 4; ++br)
        preBytes += ((long)BATCH * N * dfs[br] + (long)HH * dfs[br] * dfs[br]
                    + (long)dfs[br] * dfs[br]) * 2;
    const long perG = (long)HH * KVP * N * 2      // KT   (Sacat aliases KT+Qcat)
                    + (long)HH * ECAT * N * 2     // Qcat
                    + (long)HH * N * KVP * 2      // V
                    + (long)HH * ECAT * KVP * 4;  // Scat (Chcat aliases this)
    int G = 8;
    while (G > 1 && preBytes + (long)G * perG + 65536 > (long)ws_size) G >>= 1;

    // ---- carve workspace (KTb and Qb contiguous: Sab aliases their union)
    char* p = (char*)d_ws;
    short* embAllp = (short*)p; p += eAll * 2;
    short* embp[4]; short* WQp[4]; short* WOp[4];
    for (int br = 0; br < 4; ++br) { embp[br] = (short*)p; p += (long)BATCH * N * dfs[br] * 2; }
    for (int br = 0; br < 4; ++br) { WQp[br]  = (short*)p; p += (long)HH * dfs[br] * dfs[br] * 2; }
    short* WKp = (short*)p; p += eWKp * 2;
    short* WVp = (short*)p; p += eWKp * 2;
    for (int br = 0; br < 4; ++br) { WOp[br]  = (short*)p; p += (long)dfs[br] * dfs[br] * 2; }
    short* KTb = (short*)p; p += (long)G * HH * KVP * N * 2;
    short* Qb  = (short*)p; p += (long)G * HH * ECAT * N * 2;    // Qcat
    short* Vb  = (short*)p; p += (long)G * HH * N * KVP * 2;
    float* Sb  = (float*)p; p += (long)G * HH * ECAT * KVP * 4;  // Scat
    float* statsAcc = (float*)p; p += (long)BATCH * HH * 4 * 2 * 4;
    short* Sab = (short*)KTb;  // Sacat aliases KT+Qcat (dead after S GEMM)
    short* Chb = (short*)Sb;   // Chcat aliases Scat (dead after softmax)

    // ---- ONE convert launch: 13 plain segments + 2 padded-W segments
    {
        ConvJobs J;
        long cum = 0; int sg = 0;
        auto addJob = [&](const float* src, short* dst, long nunits, int ty) {
            J.src[sg] = src; J.dst[sg] = dst; J.cum[sg] = cum; J.type[sg] = ty;
            cum += nunits; ++sg;
        };
        addJob(emb_all, embAllp, eAll / 8, 0);
        for (int br = 0; br < 4; ++br) addJob(emb[br], embp[br], (long)BATCH * N * dfs[br] / 8, 0);
        for (int br = 0; br < 4; ++br) addJob(WQ[br], WQp[br], (long)HH * dfs[br] * dfs[br] / 8, 0);
        for (int br = 0; br < 4; ++br) addJob(WO[br], WOp[br], (long)dfs[br] * dfs[br] / 8, 0);
        addJob(WK, WKp, (long)HH * KVP * (KVD / 8), 1);
        addJob(WV, WVp, (long)HH * KVP * (KVD / 8), 1);
        J.cum[15] = cum;
        J.statsAcc = statsAcc;
        J.nAcc = BATCH * HH * 4 * 2;    // 256 — zero every b0 slice up front
        conv_all_kernel<<<dim3((unsigned)((cum + 255) / 256)), dim3(256), 0, stream>>>(J);
    }

    const float scale = 1.0f / sqrtf((float)KVD);
    long outBase[4];
    {
        long acc = 0;
        for (int br = 0; br < 4; ++br) { outBase[br] = acc; acc += (long)BATCH * N * dfs[br]; }
    }

    const dim3 blk(256), blk8(512);
    int it = 0;
    for (int b0 = 0; b0 < BATCH; b0 += G, ++it) {
        const int Z = G * HH;
        const short* embA = embAllp + (long)b0 * N * KVD;
        float* accIt = statsAcc + (long)it * Z * 4 * 2;

        // ---- KT + V on the 8-phase kernel (one job table) ---------------------
        {
            GemmJobs J; J.njobs = 2;
            GemmJob& k = J.j[0];
            k.A = WKp; k.B = embA; k.C = KTb; k.alpha = 1.0f;
            k.lda = KVD; k.ldb = KVD; k.ldc = (int)N; k.K = KVD; k.inner = 1;
            k.sA = 0; k.sB = 0;
            k.zAh = (long)KVP * KVD; k.zAg = 0;
            k.zBh = 0;               k.zBg = (long)N * KVD;
            k.zCh = (long)KVP * N;   k.zCg = (long)HH * KVP * N;
            k.splitH = 1; k.gx = 4; k.gy = 4; k.Z = Z; k.cfg = 0; k.blkBase = 0;
            GemmJob& v = J.j[1];
            v.A = embA; v.B = WVp; v.C = Vb; v.alpha = 1.0f;
            v.lda = KVD; v.ldb = KVD; v.ldc = KVP; v.K = KVD; v.inner = 1;
            v.sA = 0; v.sB = 0;
            v.zAh = 0;               v.zAg = (long)N * KVD;
            v.zBh = (long)KVP * KVD; v.zBg = 0;
            v.zCh = (long)N * KVP;   v.zCg = (long)HH * N * KVP;
            v.splitH = 1; v.gx = 4; v.gy = 4; v.Z = Z; v.cfg = 0; v.blkBase = 16 * Z;
            mfma8<short, 0><<<dim3(32 * Z), blk8, 0, stream>>>(J, nullptr);
        }

        // ---- Q branches (legacy job-table) -> concat rows of Qcat -------------
        {
            GemmJobs J; int nj = 0; int base = 0;
            for (int br = 3; br >= 0; --br) {       // big df first
                const int df = dfs[br];
                const short* embB = embp[br] + (long)b0 * N * df;
                short* Qdst = Qb + (long)rowoff[br] * N;
                GemmJob& q = J.j[nj];
                q.A = WQp[br]; q.B = embB; q.C = Qdst; q.alpha = 1.0f;
                q.lda = df; q.ldb = df; q.ldc = (int)N; q.K = df; q.inner = 1;
                q.sA = 0; q.sB = 0;
                q.zAh = (long)df * df; q.zAg = 0;
                q.zBh = 0;             q.zBg = (long)N * df;
                q.zCh = (long)ECAT * N; q.zCg = (long)HH * ECAT * N;
                q.splitH = 1; q.Z = Z; q.gx = 8;
                if (df >= 128) { q.cfg = 0; q.gy = df / 128; }
                else           { q.cfg = 2; q.gy = 1;        }
                q.blkBase = base;
                base += q.gx * q.gy * Z;
                ++nj;
            }
            J.njobs = nj;
            mfma_jt<short><<<dim3(base), blk, 0, stream>>>(J);
        }

        // ---- S on the 8-phase kernel (fused instance-norm stats) --------------
        {
            GemmJobs J; J.njobs = 1;
            GemmJob& s = J.j[0];
            s.A = Qb; s.B = KTb; s.C = Sb; s.alpha = scale;
            s.lda = (int)N; s.ldb = (int)N; s.ldc = KVP; s.K = (int)N; s.inner = 1;
            s.sA = 0; s.sB = 0;
            s.zAh = (long)ECAT * N;  s.zAg = (long)HH * ECAT * N;
            s.zBh = (long)KVP * N;   s.zBg = (long)HH * KVP * N;
            s.zCh = (long)ECAT * KVP; s.zCg = (long)HH * ECAT * KVP;
            s.splitH = 1; s.gx = 4; s.gy = 4; s.Z = Z; s.cfg = 0; s.blkBase = 0;
            mfma8<float, 1><<<dim3(16 * Z), blk8, 0, stream>>>(J, accIt);
        }

        // softmax (stats finalize inlined); writes Sab over dead KT+Qcat
        softmax_kernel<<<dim3(ECAT, Z), dim3(256), 0, stream>>>(Sb, Sab, accIt);

        // ---- Ch on the 8-phase kernel -----------------------------------------
        {
            GemmJobs J; J.njobs = 1;
            GemmJob& c = J.j[0];
            c.A = Vb; c.B = Sab; c.C = Chb; c.alpha = 1.0f;
            c.lda = KVP; c.ldb = KVP; c.ldc = ECAT; c.K = KVP; c.inner = 1;
            c.sA = 0; c.sB = 0;
            c.zAh = (long)N * KVP;   c.zAg = (long)HH * N * KVP;
            c.zBh = (long)ECAT * KVP; c.zBg = (long)HH * ECAT * KVP;
            c.zCh = (long)N * ECAT;  c.zCg = (long)HH * N * ECAT;
            c.splitH = 1; c.gx = 4; c.gy = 4; c.Z = Z; c.cfg = 0; c.blkBase = 0;
            mfma8<short, 0><<<dim3(16 * Z), blk8, 0, stream>>>(J, nullptr);
        }

        // ---- O mega-launch: 4 branches, one job table (legacy) ----------------
        {
            GemmJobs J; int nj = 0; int base = 0;
            for (int br = 3; br >= 0; --br) {       // big df first
                const int df = dfs[br];
                const short* Asrc = Chb + rowoff[br];
                float* Cout = out + outBase[br] + (long)b0 * N * df;
                GemmJob& q = J.j[nj];
                q.A = Asrc; q.B = WOp[br]; q.C = Cout; q.alpha = 1.0f / HH;
                q.lda = ECAT; q.ldb = df; q.ldc = df; q.K = df; q.inner = HH;
                q.sA = (long)N * ECAT; q.sB = 0;
                q.zAh = 0; q.zAg = (long)HH * N * ECAT; q.zBh = 0; q.zBg = 0;
                q.zCh = 0; q.zCg = (long)N * df;
                q.splitH = 0; q.Z = G; q.gy = 8;
                if (df >= 128) { q.cfg = 0; q.gx = df / 128; }
                else           { q.cfg = 1; q.gx = 1;        }
                q.blkBase = base;
                base += q.gx * q.gy * G;
                ++nj;
            }
            J.njobs = nj;
            mfma_jt<float><<<dim3(base), blk, 0, stream>>>(J);
        }
    }
}

// Round 4
// 633.524 us; speedup vs baseline: 1.7436x; 1.0189x over previous
//
#include <hip/hip_runtime.h>
#include <hip/hip_bf16.h>
#include <math.h>

#define HH    4
#define NSEQ  1024
#define KVD   960    // true KV dim
#define KVP   1024   // padded KV dim (zero pad) so every tile dim is 128-divisible
#define BATCH 8
#define ECAT  1024   // concat of branch channel dims (960 real, 64 pad rows)

static constexpr float EPS = 1e-5f;

typedef __attribute__((ext_vector_type(8))) short short8;   // 8 bf16
typedef __attribute__((ext_vector_type(4))) short short4e;  // 4 bf16
typedef __attribute__((ext_vector_type(4))) float f32x4;    // MFMA C/D frag

__device__ __forceinline__ short f2bf(float x) {
    union { __hip_bfloat16 h; short s; } u;
    u.h = __float2bfloat16(x);
    return u.s;
}
__device__ __forceinline__ short8 cvt8(const float* __restrict__ g) {
    const float4 a = *(const float4*)g;
    const float4 b = *(const float4*)(g + 4);
    short8 t;
    t[0] = f2bf(a.x); t[1] = f2bf(a.y); t[2] = f2bf(a.z); t[3] = f2bf(a.w);
    t[4] = f2bf(b.x); t[5] = f2bf(b.y); t[6] = f2bf(b.z); t[7] = f2bf(b.w);
    return t;
}

// ---- one-time input converts: 15 segments (13 plain + 2 padded-W) in ONE launch
struct ConvJobs {
    const float* src[15];
    short*       dst[15];
    long         cum[16];
    int          type[15];   // 0 = plain copy, 1 = padded WK/WV layout
    float*       statsAcc;   // zero-init side effect (block 0)
    int          nAcc;
};

__global__ void conv_all_kernel(ConvJobs J)
{
    if (blockIdx.x == 0 && threadIdx.x < (unsigned)J.nAcc)
        J.statsAcc[threadIdx.x] = 0.f;
    const long u = (long)blockIdx.x * 256 + threadIdx.x;
    if (u >= J.cum[15]) return;
    int sg = 0;
    while (u >= J.cum[sg + 1]) ++sg;
    const long l = u - J.cum[sg];
    if (J.type[sg] == 0) {
        *(short8*)(J.dst[sg] + l * 8) = cvt8(J.src[sg] + l * 8);
    } else {
        const int cpr = KVD / 8;                              // 120
        const int c8  = (int)(l % cpr) * 8;
        const int row = (int)((l / cpr) % KVP);
        const int h   = (int)(l / ((long)cpr * KVP));
        short8 t = (short8){0,0,0,0,0,0,0,0};
        if (row < KVD) t = cvt8(J.src[sg] + ((long)h * KVD + row) * KVD + c8);
        *(short8*)(J.dst[sg] + ((long)h * KVP + row) * KVD + c8) = t;
    }
}

// ---- legacy async LDS staging: ROWS x 32 bf16, 64B rows, chunk-XOR swizzle.
template<int ROWS>
__device__ __forceinline__ void stage_async(short (*dst)[32], const short* __restrict__ src,
                                            int ld, int w, int lane)
{
    #pragma unroll
    for (int p = 0; p < ROWS / 64; ++p) {
        const int rbase = p * 64 + w * 16;
        const int row   = rbase + (lane >> 2);
        const int c16l  = ((lane & 3) - row) & 3;
        const short* g  = src + (long)row * ld + c16l * 8;
        __builtin_amdgcn_global_load_lds(
            (const __attribute__((address_space(1))) void*)g,
            (__attribute__((address_space(3))) void*)&dst[rbase][0],
            16, 0, 0);
    }
}

// ---------------------------------------------------------------------------
struct GemmJob {
    const short* A; const short* B; void* C;
    float alpha;
    int lda, ldb, ldc, K, inner, gx, gy, Z, splitH, cfg, blkBase, pad0;
    long sA, sB, zAh, zAg, zBh, zBg, zCh, zCg;
};
struct GemmJobs { GemmJob j[8]; int njobs; };

// ---- legacy 128^2 GEMM body (verified): C = alpha * sum_ib A[M,K] @ B[Nc,K]^T
template<int TM, int TN, typename TC>
__device__ __forceinline__ void gemm_body(const GemmJob& job, int lb,
                                          short (*As)[32], short (*Bs)[32])
{
    constexpr int MT = TM / 32;
    constexpr int NT = TN / 32;
    const short* A = job.A;
    const short* B = job.B;
    TC* C = (TC*)job.C;
    const int bps = job.gx * job.gy;
    const int Z   = job.Z;
    int z, r;
    if ((Z & 7) == 0) {
        const int xcd = lb & 7;
        const int j   = lb >> 3;
        const int spx = Z >> 3;
        z = xcd * spx + j / bps;
        r = j % bps;
    } else {
        z = lb / bps;
        r = lb % bps;
    }
    const int x = r % job.gx, y = r / job.gx;
    int h, g;
    if (job.splitH) { h = z & (HH - 1); g = z >> 2; }
    else            { h = 0;            g = z;      }
    A += (long)h * job.zAh + (long)g * job.zAg;
    B += (long)h * job.zBh + (long)g * job.zBg;
    C += (long)h * job.zCh + (long)g * job.zCg;

    const int tid  = threadIdx.x;
    const int lane = tid & 63;
    const int w    = tid >> 6;
    const int wr   = w >> 1;
    const int wc   = w & 1;
    const int quad = lane >> 4;
    const int l16  = lane & 15;
    const long m0  = (long)y * TM;
    const long n0  = (long)x * TN;

    f32x4 acc[MT][NT];
    #pragma unroll
    for (int i = 0; i < MT; ++i)
        #pragma unroll
        for (int j2 = 0; j2 < NT; ++j2)
            acc[i][j2] = (f32x4){0.f, 0.f, 0.f, 0.f};

    for (int ib = 0; ib < job.inner; ++ib) {
        const short* Ab = A + (long)ib * job.sA + m0 * job.lda;
        const short* Bb = B + (long)ib * job.sB + n0 * job.ldb;
        for (int k0 = 0; k0 < job.K; k0 += 32) {
            stage_async<TM>(As, Ab + k0, job.lda, w, lane);
            stage_async<TN>(Bs, Bb + k0, job.ldb, w, lane);
            __syncthreads();
            short8 af[MT], bfr[NT];
            #pragma unroll
            for (int i = 0; i < MT; ++i) {
                const int rowA = wr * (TM / 2) + i * 16 + l16;
                af[i] = *(const short8*)&As[rowA][((quad + rowA) & 3) * 8];
            }
            #pragma unroll
            for (int j2 = 0; j2 < NT; ++j2) {
                const int rowB = wc * (TN / 2) + j2 * 16 + l16;
                bfr[j2] = *(const short8*)&Bs[rowB][((quad + rowB) & 3) * 8];
            }
            #pragma unroll
            for (int i = 0; i < MT; ++i)
                #pragma unroll
                for (int j2 = 0; j2 < NT; ++j2)
                    acc[i][j2] = __builtin_amdgcn_mfma_f32_16x16x32_bf16(
                        af[i], bfr[j2], acc[i][j2], 0, 0, 0);
            __syncthreads();
        }
    }

    #pragma unroll
    for (int i = 0; i < MT; ++i) {
        #pragma unroll
        for (int j2 = 0; j2 < NT; ++j2) {
            const long row = m0 + wr * (TM / 2) + i * 16 + quad * 4;
            const long col = n0 + wc * (TN / 2) + j2 * 16 + l16;
            #pragma unroll
            for (int rr = 0; rr < 4; ++rr) {
                const float v = job.alpha * acc[i][j2][rr];
                if constexpr (sizeof(TC) == 4)
                    C[(row + rr) * job.ldc + col] = v;
                else
                    C[(row + rr) * job.ldc + col] = f2bf(v);
            }
        }
    }
}

template<typename TC>
__global__ __launch_bounds__(256) void mfma_jt(GemmJobs J)
{
    __shared__ short As[128][32];
    __shared__ short Bs[128][32];
    const int bid = blockIdx.x;
    int ji = 0;
    while (ji + 1 < J.njobs && bid >= J.j[ji + 1].blkBase) ++ji;
    const GemmJob& job = J.j[ji];
    const int lb = bid - job.blkBase;
    switch (job.cfg) {
        case 0: gemm_body<128, 128, TC>(job, lb, As, Bs); break;
        case 1: gemm_body<128,  64, TC>(job, lb, As, Bs); break;
        default: gemm_body<64, 128, TC>(job, lb, As, Bs); break;
    }
}

// ---------------------------------------------------------------------------
// 256^2-tile, BK=64, 8-wave, 8-phase bf16 NT GEMM, counted vmcnt — round-3
// schedule with ADDRESSING HOISTED: K-loop unrolled x2 so buffer parity q is
// compile-time; 12 LDS fragment base addrs live in VGPRs and every ds_read is
// a single instruction with offset:imm (q*32768 + half*16384 bytes <= 65520);
// 8 global stage pointers bump +128B per stage. A-fragments reused across the
// (aa,0)/(aa,1) phase pair: 32 ds_read_b128 per K-tile (was 48).
// Schedule per K-tile t (buf q=t&1), phases = C-quadrants (0,0)(0,1)(1,0)(1,1):
//   ph1 stages (t+1)A1 -> buf q^1, ph2 (t+1)B1 -> q^1,
//   ph3 stages (t+2)A0 -> buf q (A0's last reader is ph2),
//   ph4 stages (t+2)B0 -> buf q (B0's last reader is ph3), then vmcnt(4):
//   tile t+1 fully resident, t+2's A0/B0 stay in flight across the boundary.
// ---------------------------------------------------------------------------
#define STAGE(Pa, Pb, DST) do {                                                  \
    __builtin_amdgcn_global_load_lds(                                            \
        (const __attribute__((address_space(1))) void*)(Pa),                     \
        (__attribute__((address_space(3))) void*)(DST), 16, 0, 0);               \
    __builtin_amdgcn_global_load_lds(                                            \
        (const __attribute__((address_space(1))) void*)(Pb),                     \
        (__attribute__((address_space(3))) void*)((DST) + 4096), 16, 0, 0);      \
    (Pa) += 64; (Pb) += 64;                                                      \
} while (0)

// phase with A+B fragment loads (af_ declared at TILE scope)
#define PHA(Q, AA, BB, ...) do {                                                 \
    short8 bf_[2][2];                                                            \
    _Pragma("unroll")                                                            \
    for (int mi_ = 0; mi_ < 4; ++mi_)                                            \
        _Pragma("unroll")                                                        \
        for (int ks_ = 0; ks_ < 2; ++ks_)                                        \
            af_[mi_][ks_] = *(const short8*)(paf0[mi_][ks_] + (Q)*16384 + (AA)*8192); \
    _Pragma("unroll")                                                            \
    for (int nj_ = 0; nj_ < 2; ++nj_)                                            \
        _Pragma("unroll")                                                        \
        for (int ks_ = 0; ks_ < 2; ++ks_)                                        \
            bf_[nj_][ks_] = *(const short8*)(pbf0[nj_][ks_] + (Q)*16384 + (BB)*8192); \
    __VA_ARGS__;                                                                 \
    __builtin_amdgcn_s_barrier();                                                \
    asm volatile("s_waitcnt lgkmcnt(0)" ::: "memory");                           \
    __builtin_amdgcn_sched_barrier(0);                                           \
    __builtin_amdgcn_s_setprio(1);                                               \
    _Pragma("unroll")                                                            \
    for (int mi_ = 0; mi_ < 4; ++mi_)                                            \
        _Pragma("unroll")                                                        \
        for (int nj_ = 0; nj_ < 2; ++nj_) {                                      \
            acc[(AA)*4 + mi_][(BB)*2 + nj_] = __builtin_amdgcn_mfma_f32_16x16x32_bf16( \
                af_[mi_][0], bf_[nj_][0], acc[(AA)*4 + mi_][(BB)*2 + nj_], 0, 0, 0);   \
            acc[(AA)*4 + mi_][(BB)*2 + nj_] = __builtin_amdgcn_mfma_f32_16x16x32_bf16( \
                af_[mi_][1], bf_[nj_][1], acc[(AA)*4 + mi_][(BB)*2 + nj_], 0, 0, 0);   \
        }                                                                        \
    __builtin_amdgcn_s_setprio(0);                                               \
    __builtin_amdgcn_s_barrier();                                                \
} while (0)

// phase reusing af_ from the preceding PHA (loads only B fragments)
#define PHB(Q, AA, BB, ...) do {                                                 \
    short8 bf_[2][2];                                                            \
    _Pragma("unroll")                                                            \
    for (int nj_ = 0; nj_ < 2; ++nj_)                                            \
        _Pragma("unroll")                                                        \
        for (int ks_ = 0; ks_ < 2; ++ks_)                                        \
            bf_[nj_][ks_] = *(const short8*)(pbf0[nj_][ks_] + (Q)*16384 + (BB)*8192); \
    __VA_ARGS__;                                                                 \
    __builtin_amdgcn_s_barrier();                                                \
    asm volatile("s_waitcnt lgkmcnt(0)" ::: "memory");                           \
    __builtin_amdgcn_sched_barrier(0);                                           \
    __builtin_amdgcn_s_setprio(1);                                               \
    _Pragma("unroll")                                                            \
    for (int mi_ = 0; mi_ < 4; ++mi_)                                            \
        _Pragma("unroll")                                                        \
        for (int nj_ = 0; nj_ < 2; ++nj_) {                                      \
            acc[(AA)*4 + mi_][(BB)*2 + nj_] = __builtin_amdgcn_mfma_f32_16x16x32_bf16( \
                af_[mi_][0], bf_[nj_][0], acc[(AA)*4 + mi_][(BB)*2 + nj_], 0, 0, 0);   \
            acc[(AA)*4 + mi_][(BB)*2 + nj_] = __builtin_amdgcn_mfma_f32_16x16x32_bf16( \
                af_[mi_][1], bf_[nj_][1], acc[(AA)*4 + mi_][(BB)*2 + nj_], 0, 0, 0);   \
        }                                                                        \
    __builtin_amdgcn_s_setprio(0);                                               \
    __builtin_amdgcn_s_barrier();                                                \
} while (0)

#define TILE(Q, T) do {                                                          \
    short8 af_[4][2];                                                            \
    PHA(Q, 0, 0, { if ((T) + 1 < NT) STAGE(gA1a, gA1b, &AT[1-(Q)][1][0][0] + dofs); }); \
    PHB(Q, 0, 1, { if ((T) + 1 < NT) STAGE(gB1a, gB1b, &BT[1-(Q)][1][0][0] + dofs); }); \
    PHA(Q, 1, 0, { if ((T) + 2 < NT) STAGE(gA0a, gA0b, &AT[(Q)][0][0][0] + dofs); });   \
    PHB(Q, 1, 1, {                                                               \
        if ((T) + 2 < NT) {                                                      \
            STAGE(gB0a, gB0b, &BT[(Q)][0][0][0] + dofs);                         \
            asm volatile("s_waitcnt vmcnt(4)" ::: "memory");                     \
        } else {                                                                 \
            asm volatile("s_waitcnt vmcnt(0)" ::: "memory");                     \
        } });                                                                    \
} while (0)

template<typename TC, int STATS>
__global__ __launch_bounds__(512, 2) void mfma8(GemmJobs J, float* __restrict__ statsAcc)
{
    __shared__ short AT[2][2][128][64];
    __shared__ short BT[2][2][128][64];

    const int bid = blockIdx.x;
    int ji = 0;
    while (ji + 1 < J.njobs && bid >= J.j[ji + 1].blkBase) ++ji;
    const GemmJob& job = J.j[ji];
    const int lb = bid - job.blkBase;
    const int Z  = job.Z;
    const int gx = job.gx;
    const int bps = gx * job.gy;
    int z, r;
    if ((Z & 7) == 0) {
        const int xcd = lb & 7;
        const int jj  = lb >> 3;
        const int spx = Z >> 3;
        z = xcd * spx + jj / bps;
        r = jj % bps;
    } else {
        z = lb / bps;
        r = lb % bps;
    }
    const int x = r % gx, y = r / gx;
    int h, g;
    if (job.splitH) { h = z & (HH - 1); g = z >> 2; }
    else            { h = 0;            g = z;      }
    const int lda = job.lda, ldb = job.ldb, ldc = job.ldc;
    const short* A = job.A + (long)h * job.zAh + (long)g * job.zAg + (long)(y * 256) * lda;
    const short* B = job.B + (long)h * job.zBh + (long)g * job.zBg + (long)(x * 256) * ldb;
    TC* C = (TC*)job.C + (long)h * job.zCh + (long)g * job.zCg;
    const int NT = job.K >> 6;

    const int tid  = threadIdx.x;
    const int lane = tid & 63;
    const int w    = tid >> 6;
    const int wm   = w >> 2;        // 0..1
    const int wn   = w & 3;         // 0..3
    const int quad = lane >> 4;
    const int l16  = lane & 15;
    const int dofs = w * 512;       // LDS short-offset of this wave's 1KB stage slot

    // global stage pointers (per-lane, chunk-rotation pre-swizzled [m104/m173])
    const int o16 = w * 64 + lane;
    const int rS  = o16 >> 3;
    const int pcS = o16 & 7;
    const int lcS = ((pcS - rS) & 7) * 8;
    const short* gA0a = A + (long)rS * lda + lcS;
    const short* gA0b = A + (long)(rS + 64) * lda + lcS;
    const short* gA1a = gA0a + 128 * lda;
    const short* gA1b = gA0b + 128 * lda;
    const short* gB0a = B + (long)rS * ldb + lcS;
    const short* gB0b = B + (long)(rS + 64) * ldb + lcS;
    const short* gB1a = gB0a + 128 * ldb;
    const short* gB1b = gB0b + 128 * ldb;

    // hoisted LDS fragment base addresses (q=0, half=0)
    const short* paf0[4][2];
    #pragma unroll
    for (int mi = 0; mi < 4; ++mi)
        #pragma unroll
        for (int ks = 0; ks < 2; ++ks) {
            const int rr = mi * 32 + wm * 16 + l16;
            paf0[mi][ks] = &AT[0][0][rr][((ks * 4 + quad + rr) & 7) * 8];
        }
    const short* pbf0[2][2];
    #pragma unroll
    for (int nj = 0; nj < 2; ++nj)
        #pragma unroll
        for (int ks = 0; ks < 2; ++ks) {
            const int rr = nj * 64 + wn * 16 + l16;
            pbf0[nj][ks] = &BT[0][0][rr][((ks * 4 + quad + rr) & 7) * 8];
        }

    f32x4 acc[8][4];
    #pragma unroll
    for (int i = 0; i < 8; ++i)
        #pragma unroll
        for (int j2 = 0; j2 < 4; ++j2)
            acc[i][j2] = (f32x4){0.f, 0.f, 0.f, 0.f};

    // prologue: tile0 all 4 halves + tile1 A0/B0; drain tile0, keep tile1 in flight
    STAGE(gA0a, gA0b, &AT[0][0][0][0] + dofs);
    STAGE(gA1a, gA1b, &AT[0][1][0][0] + dofs);
    STAGE(gB0a, gB0b, &BT[0][0][0][0] + dofs);
    STAGE(gB1a, gB1b, &BT[0][1][0][0] + dofs);
    STAGE(gA0a, gA0b, &AT[1][0][0][0] + dofs);   // NT >= 4 in all uses
    STAGE(gB0a, gB0b, &BT[1][0][0][0] + dofs);
    asm volatile("s_waitcnt vmcnt(4)" ::: "memory");
    __builtin_amdgcn_s_barrier();

    const int NPAIR = NT >> 1;
    for (int tt = 0; tt < NPAIR; ++tt) {
        const int t0 = tt * 2;
        TILE(0, t0);
        TILE(1, t0 + 1);
    }
    if (NT & 1) TILE(0, NT - 1);

    // epilogue: C/D layout col=lane&15, row=(lane>>4)*4+reg [m89-verified]
    float s0 = 0.f, ss0 = 0.f, s1 = 0.f, ss1 = 0.f;   // buckets: rows<896, rows 896..959
    #pragma unroll
    for (int mi = 0; mi < 8; ++mi) {
        #pragma unroll
        for (int nj = 0; nj < 4; ++nj) {
            const long row = (long)y * 256 + mi * 32 + wm * 16 + quad * 4;
            const long col = (long)x * 256 + nj * 64 + wn * 16 + l16;
            #pragma unroll
            for (int rr = 0; rr < 4; ++rr) {
                const float v = job.alpha * acc[mi][nj][rr];
                if constexpr (sizeof(TC) == 4)
                    C[(row + rr) * ldc + col] = v;
                else
                    C[(row + rr) * ldc + col] = f2bf(v);
                if constexpr (STATS) {
                    const long gr = row + rr;
                    if (gr < 896)          { s0 += v; ss0 += v * v; }
                    else if (gr < KVD)     { s1 += v; ss1 += v * v; }
                }
            }
        }
    }
    if constexpr (STATS) {
        __syncthreads();
        float* red = (float*)&AT[0][0][0][0];
        red[tid] = s0; red[512 + tid] = ss0; red[1024 + tid] = s1; red[1536 + tid] = ss1;
        __syncthreads();
        for (int o = 256; o > 0; o >>= 1) {
            if (tid < o) {
                red[tid]        += red[tid + o];
                red[512 + tid]  += red[512 + tid + o];
                red[1024 + tid] += red[1024 + tid + o];
                red[1536 + tid] += red[1536 + tid + o];
            }
            __syncthreads();
        }
        if (tid == 0) {
            const int m0g = y * 256;
            const int bA = (m0g >= 768) ? 1 : (m0g >= 512) ? 2 : 3;
            atomicAdd(&statsAcc[((long)z * 4 + bA) * 2],     red[0]);
            atomicAdd(&statsAcc[((long)z * 4 + bA) * 2 + 1], red[512]);
            if (y == 3) {   // rows 896..959 -> branch 0 (df=64)
                atomicAdd(&statsAcc[((long)z * 4 + 0) * 2],     red[1024]);
                atomicAdd(&statsAcc[((long)z * 4 + 0) * 2 + 1], red[1536]);
            }
        }
    }
}

// ---- softmax over real 960 cols; stats finalize inlined (reads atomic sums).
__global__ void softmax_kernel(const float* __restrict__ S,
                               short* __restrict__ Sa,
                               const float* __restrict__ acc)
{
    const int row = blockIdx.x;          // 0..1023 concat rows (>=960 = pad)
    const int y   = blockIdx.y;
    const int t   = threadIdx.x;
    short* orow = Sa + ((long)y * ECAT + row) * KVP;
    if (row >= KVD) {                    // zero pad row (clean B-operand for Ch)
        *(short4e*)(orow + 4 * t) = (short4e){0, 0, 0, 0};
        return;
    }
    const int bidx = (row >= 896) ? 0 : (row >= 768) ? 1 : (row >= 512) ? 2 : 3;
    const int dftab[4] = {64, 128, 256, 512};
    const float sum0 = acc[((long)y * 4 + bidx) * 2];
    const float ssq0 = acc[((long)y * 4 + bidx) * 2 + 1];
    const float n    = (float)(dftab[bidx] * KVD);
    const float mean = sum0 / n;
    const float rstd = rsqrtf(ssq0 / n - mean * mean + EPS);
    const float* srow = S + ((long)y * ECAT + row) * KVP;

    const bool real = (t < KVD / 4);     // threads 0..239 hold real cols (4 each)
    float x[4];
    float mx = -1e30f;
    if (real) {
        const float4 v = *(const float4*)(srow + 4 * t);
        x[0] = (v.x - mean) * rstd; x[1] = (v.y - mean) * rstd;
        x[2] = (v.z - mean) * rstd; x[3] = (v.w - mean) * rstd;
        mx = fmaxf(fmaxf(x[0], x[1]), fmaxf(x[2], x[3]));
    }
    __shared__ float red[256];
    red[t] = mx; __syncthreads();
    for (int o = 128; o > 0; o >>= 1) {
        if (t < o) red[t] = fmaxf(red[t], red[t + o]);
        __syncthreads();
    }
    mx = red[0];
    __syncthreads();

    float e[4] = {0.f, 0.f, 0.f, 0.f};
    float sum = 0.f;
    if (real) {
        e[0] = __expf(x[0] - mx); e[1] = __expf(x[1] - mx);
        e[2] = __expf(x[2] - mx); e[3] = __expf(x[3] - mx);
        sum = e[0] + e[1] + e[2] + e[3];
    }
    red[t] = sum; __syncthreads();
    for (int o = 128; o > 0; o >>= 1) {
        if (t < o) red[t] += red[t + o];
        __syncthreads();
    }
    const float inv = 1.0f / red[0];
    short4e o4;
    o4[0] = f2bf(e[0] * inv); o4[1] = f2bf(e[1] * inv);
    o4[2] = f2bf(e[2] * inv); o4[3] = f2bf(e[3] * inv);
    *(short4e*)(orow + 4 * t) = o4;
}

// ---------------------------------------------------------------------------
extern "C" void kernel_launch(void* const* d_in, const int* in_sizes, int n_in,
                              void* d_out, int out_size, void* d_ws, size_t ws_size,
                              hipStream_t stream)
{
    (void)in_sizes; (void)n_in; (void)out_size;
    const float* emb[4]  = {(const float*)d_in[0], (const float*)d_in[1],
                            (const float*)d_in[2], (const float*)d_in[3]};
    const float* emb_all = (const float*)d_in[4];
    const float* WQ[4]   = {(const float*)d_in[5], (const float*)d_in[6],
                            (const float*)d_in[7], (const float*)d_in[8]};
    const float* WK      = (const float*)d_in[9];
    const float* WV      = (const float*)d_in[10];
    const float* WO[4]   = {(const float*)d_in[11], (const float*)d_in[12],
                            (const float*)d_in[13], (const float*)d_in[14]};
    float* out = (float*)d_out;

    const int dfs[4]    = {64, 128, 256, 512};
    const int rowoff[4] = {896, 768, 512, 0};   // concat offsets (tile-aligned)
    const long N = NSEQ;

    // ---- workspace budget (Sacat aliases KT+Qcat; Chcat aliases Scat)
    const long eAll = (long)BATCH * N * KVD;
    const long eWKp = (long)HH * KVP * KVD;
    long preBytes = eAll * 2 + 2 * eWKp * 2;
    for (int br = 0; br < 4; ++br)
        preBytes += ((long)BATCH * N * dfs[br] + (long)HH * dfs[br] * dfs[br]
                    + (long)dfs[br] * dfs[br]) * 2;
    const long perG = (long)HH * KVP * N * 2
                    + (long)HH * ECAT * N * 2
                    + (long)HH * N * KVP * 2
                    + (long)HH * ECAT * KVP * 4;
    int G = 8;
    while (G > 1 && preBytes + (long)G * perG + 65536 > (long)ws_size) G >>= 1;

    // ---- carve workspace (KTb and Qb contiguous: Sab aliases their union)
    char* p = (char*)d_ws;
    short* embAllp = (short*)p; p += eAll * 2;
    short* embp[4]; short* WQp[4]; short* WOp[4];
    for (int br = 0; br < 4; ++br) { embp[br] = (short*)p; p += (long)BATCH * N * dfs[br] * 2; }
    for (int br = 0; br < 4; ++br) { WQp[br]  = (short*)p; p += (long)HH * dfs[br] * dfs[br] * 2; }
    short* WKp = (short*)p; p += eWKp * 2;
    short* WVp = (short*)p; p += eWKp * 2;
    for (int br = 0; br < 4; ++br) { WOp[br]  = (short*)p; p += (long)dfs[br] * dfs[br] * 2; }
    short* KTb = (short*)p; p += (long)G * HH * KVP * N * 2;
    short* Qb  = (short*)p; p += (long)G * HH * ECAT * N * 2;    // Qcat
    short* Vb  = (short*)p; p += (long)G * HH * N * KVP * 2;
    float* Sb  = (float*)p; p += (long)G * HH * ECAT * KVP * 4;  // Scat
    float* statsAcc = (float*)p; p += (long)BATCH * HH * 4 * 2 * 4;
    short* Sab = (short*)KTb;  // Sacat aliases KT+Qcat (dead after S GEMM)
    short* Chb = (short*)Sb;   // Chcat aliases Scat (dead after softmax)

    // ---- ONE convert launch: 13 plain segments + 2 padded-W segments
    {
        ConvJobs J;
        long cum = 0; int sg = 0;
        auto addJob = [&](const float* src, short* dst, long nunits, int ty) {
            J.src[sg] = src; J.dst[sg] = dst; J.cum[sg] = cum; J.type[sg] = ty;
            cum += nunits; ++sg;
        };
        addJob(emb_all, embAllp, eAll / 8, 0);
        for (int br = 0; br < 4; ++br) addJob(emb[br], embp[br], (long)BATCH * N * dfs[br] / 8, 0);
        for (int br = 0; br < 4; ++br) addJob(WQ[br], WQp[br], (long)HH * dfs[br] * dfs[br] / 8, 0);
        for (int br = 0; br < 4; ++br) addJob(WO[br], WOp[br], (long)dfs[br] * dfs[br] / 8, 0);
        addJob(WK, WKp, (long)HH * KVP * (KVD / 8), 1);
        addJob(WV, WVp, (long)HH * KVP * (KVD / 8), 1);
        J.cum[15] = cum;
        J.statsAcc = statsAcc;
        J.nAcc = BATCH * HH * 4 * 2;
        conv_all_kernel<<<dim3((unsigned)((cum + 255) / 256)), dim3(256), 0, stream>>>(J);
    }

    const float scale = 1.0f / sqrtf((float)KVD);
    long outBase[4];
    {
        long acc = 0;
        for (int br = 0; br < 4; ++br) { outBase[br] = acc; acc += (long)BATCH * N * dfs[br]; }
    }

    const dim3 blk(256), blk8(512);
    int it = 0;
    for (int b0 = 0; b0 < BATCH; b0 += G, ++it) {
        const int Z = G * HH;
        const short* embA = embAllp + (long)b0 * N * KVD;
        float* accIt = statsAcc + (long)it * Z * 4 * 2;

        // ---- mega1 on mfma8: KT + V + Q512 + Q256 (one job table) -------------
        {
            GemmJobs J; int nj = 0; int base = 0;
            auto add8 = [&](const short* A, const short* B, void* C, float alpha,
                            int lda, int ldb, int ldc, int K,
                            long zAh, long zAg, long zBh, long zBg,
                            long zCh, long zCg, int gx, int gy) {
                GemmJob& q = J.j[nj];
                q.A = A; q.B = B; q.C = C; q.alpha = alpha;
                q.lda = lda; q.ldb = ldb; q.ldc = ldc; q.K = K; q.inner = 1;
                q.sA = 0; q.sB = 0;
                q.zAh = zAh; q.zAg = zAg; q.zBh = zBh; q.zBg = zBg;
                q.zCh = zCh; q.zCg = zCg;
                q.splitH = 1; q.gx = gx; q.gy = gy; q.Z = Z; q.cfg = 0;
                q.blkBase = base;
                base += gx * gy * Z; ++nj;
            };
            // KT[g][h][j(1024)][n] = sum_k WKp[h][j][k] embA[g][n][k]
            add8(WKp, embA, KTb, 1.0f, KVD, KVD, (int)N, KVD,
                 (long)KVP * KVD, 0, 0, (long)N * KVD,
                 (long)KVP * N, (long)HH * KVP * N, 4, 4);
            // V[g][h][n][j(1024)] = sum_k embA[g][n][k] WVp[h][j][k]
            add8(embA, WVp, Vb, 1.0f, KVD, KVD, KVP, KVD,
                 0, (long)N * KVD, (long)KVP * KVD, 0,
                 (long)N * KVP, (long)HH * N * KVP, 4, 4);
            // Q512: M=512 (gy=2) -> concat rows 0..511
            add8(WQp[3], embp[3] + (long)b0 * N * 512, Qb + (long)rowoff[3] * N, 1.0f,
                 512, 512, (int)N, 512,
                 512L * 512, 0, 0, (long)N * 512,
                 (long)ECAT * N, (long)HH * ECAT * N, 4, 2);
            // Q256: M=256 (gy=1) -> concat rows 512..767
            add8(WQp[2], embp[2] + (long)b0 * N * 256, Qb + (long)rowoff[2] * N, 1.0f,
                 256, 256, (int)N, 256,
                 256L * 256, 0, 0, (long)N * 256,
                 (long)ECAT * N, (long)HH * ECAT * N, 4, 1);
            J.njobs = nj;
            mfma8<short, 0><<<dim3(base), blk8, 0, stream>>>(J, nullptr);
        }

        // ---- Q128 + Q64 (legacy job-table) -> concat rows of Qcat -------------
        {
            GemmJobs J; int nj = 0; int base = 0;
            for (int br = 1; br >= 0; --br) {
                const int df = dfs[br];
                const short* embB = embp[br] + (long)b0 * N * df;
                short* Qdst = Qb + (long)rowoff[br] * N;
                GemmJob& q = J.j[nj];
                q.A = WQp[br]; q.B = embB; q.C = Qdst; q.alpha = 1.0f;
                q.lda = df; q.ldb = df; q.ldc = (int)N; q.K = df; q.inner = 1;
                q.sA = 0; q.sB = 0;
                q.zAh = (long)df * df; q.zAg = 0;
                q.zBh = 0;             q.zBg = (long)N * df;
                q.zCh = (long)ECAT * N; q.zCg = (long)HH * ECAT * N;
                q.splitH = 1; q.Z = Z; q.gx = 8; q.gy = 1;
                q.cfg = (df >= 128) ? 0 : 2;
                q.blkBase = base;
                base += 8 * Z;
                ++nj;
            }
            J.njobs = nj;
            mfma_jt<short><<<dim3(base), blk, 0, stream>>>(J);
        }

        // ---- S on mfma8 (fused instance-norm stats) ---------------------------
        {
            GemmJobs J; J.njobs = 1;
            GemmJob& s = J.j[0];
            s.A = Qb; s.B = KTb; s.C = Sb; s.alpha = scale;
            s.lda = (int)N; s.ldb = (int)N; s.ldc = KVP; s.K = (int)N; s.inner = 1;
            s.sA = 0; s.sB = 0;
            s.zAh = (long)ECAT * N;  s.zAg = (long)HH * ECAT * N;
            s.zBh = (long)KVP * N;   s.zBg = (long)HH * KVP * N;
            s.zCh = (long)ECAT * KVP; s.zCg = (long)HH * ECAT * KVP;
            s.splitH = 1; s.gx = 4; s.gy = 4; s.Z = Z; s.cfg = 0; s.blkBase = 0;
            mfma8<float, 1><<<dim3(16 * Z), blk8, 0, stream>>>(J, accIt);
        }

        // softmax (stats finalize inlined); writes Sab over dead KT+Qcat
        softmax_kernel<<<dim3(ECAT, Z), dim3(256), 0, stream>>>(Sb, Sab, accIt);

        // ---- Ch on mfma8 ------------------------------------------------------
        {
            GemmJobs J; J.njobs = 1;
            GemmJob& c = J.j[0];
            c.A = Vb; c.B = Sab; c.C = Chb; c.alpha = 1.0f;
            c.lda = KVP; c.ldb = KVP; c.ldc = ECAT; c.K = KVP; c.inner = 1;
            c.sA = 0; c.sB = 0;
            c.zAh = (long)N * KVP;   c.zAg = (long)HH * N * KVP;
            c.zBh = (long)ECAT * KVP; c.zBg = (long)HH * ECAT * KVP;
            c.zCh = (long)N * ECAT;  c.zCg = (long)HH * N * ECAT;
            c.splitH = 1; c.gx = 4; c.gy = 4; c.Z = Z; c.cfg = 0; c.blkBase = 0;
            mfma8<short, 0><<<dim3(16 * Z), blk8, 0, stream>>>(J, nullptr);
        }

        // ---- O mega-launch: 4 branches, one job table (legacy) ----------------
        {
            GemmJobs J; int nj = 0; int base = 0;
            for (int br = 3; br >= 0; --br) {
                const int df = dfs[br];
                const short* Asrc = Chb + rowoff[br];
                float* Cout = out + outBase[br] + (long)b0 * N * df;
                GemmJob& q = J.j[nj];
                q.A = Asrc; q.B = WOp[br]; q.C = Cout; q.alpha = 1.0f / HH;
                q.lda = ECAT; q.ldb = df; q.ldc = df; q.K = df; q.inner = HH;
                q.sA = (long)N * ECAT; q.sB = 0;
                q.zAh = 0; q.zAg = (long)HH * N * ECAT; q.zBh = 0; q.zBg = 0;
                q.zCh = 0; q.zCg = (long)N * df;
                q.splitH = 0; q.Z = G; q.gy = 8;
                if (df >= 128) { q.cfg = 0; q.gx = df / 128; }
                else           { q.cfg = 1; q.gx = 1;        }
                q.blkBase = base;
                base += q.gx * q.gy * G;
                ++nj;
            }
            J.njobs = nj;
            mfma_jt<float><<<dim3(base), blk, 0, stream>>>(J);
        }
    }
}

// Round 6
// 628.632 us; speedup vs baseline: 1.7572x; 1.0078x over previous
//
#include <hip/hip_runtime.h>
#include <hip/hip_bf16.h>
#include <math.h>

#define HH    4
#define NSEQ  1024
#define KVD   960    // true KV dim
#define KVP   1024   // padded KV dim (zero pad) so every tile dim is 128-divisible
#define BATCH 8
#define ECAT  1024   // concat of branch channel dims (960 real, 64 pad rows)

static constexpr float EPS = 1e-5f;

typedef __attribute__((ext_vector_type(8))) short short8;   // 8 bf16
typedef __attribute__((ext_vector_type(4))) short short4e;  // 4 bf16
typedef __attribute__((ext_vector_type(4))) float f32x4;    // MFMA C/D frag

__device__ __forceinline__ short f2bf(float x) {
    union { __hip_bfloat16 h; short s; } u;
    u.h = __float2bfloat16(x);
    return u.s;
}
__device__ __forceinline__ short8 cvt8(const float* __restrict__ g) {
    const float4 a = *(const float4*)g;
    const float4 b = *(const float4*)(g + 4);
    short8 t;
    t[0] = f2bf(a.x); t[1] = f2bf(a.y); t[2] = f2bf(a.z); t[3] = f2bf(a.w);
    t[4] = f2bf(b.x); t[5] = f2bf(b.y); t[6] = f2bf(b.z); t[7] = f2bf(b.w);
    return t;
}

// ---- one-time input converts: 15 segments (13 plain + 2 padded-W) in ONE launch
struct ConvJobs {
    const float* src[15];
    short*       dst[15];
    long         cum[16];
    int          type[15];   // 0 = plain copy, 1 = padded WK/WV layout
    float*       statsAcc;   // zero-init side effect (block 0)
    int          nAcc;
};

__global__ void conv_all_kernel(ConvJobs J)
{
    if (blockIdx.x == 0 && threadIdx.x < (unsigned)J.nAcc)
        J.statsAcc[threadIdx.x] = 0.f;
    const long u = (long)blockIdx.x * 256 + threadIdx.x;
    if (u >= J.cum[15]) return;
    int sg = 0;
    while (u >= J.cum[sg + 1]) ++sg;
    const long l = u - J.cum[sg];
    if (J.type[sg] == 0) {
        *(short8*)(J.dst[sg] + l * 8) = cvt8(J.src[sg] + l * 8);
    } else {
        const int cpr = KVD / 8;                              // 120
        const int c8  = (int)(l % cpr) * 8;
        const int row = (int)((l / cpr) % KVP);
        const int h   = (int)(l / ((long)cpr * KVP));
        short8 t = (short8){0,0,0,0,0,0,0,0};
        if (row < KVD) t = cvt8(J.src[sg] + ((long)h * KVD + row) * KVD + c8);
        *(short8*)(J.dst[sg] + ((long)h * KVP + row) * KVD + c8) = t;
    }
}

// ---- legacy async LDS staging: ROWS x 32 bf16, 64B rows, chunk-XOR swizzle.
template<int ROWS>
__device__ __forceinline__ void stage_async(short (*dst)[32], const short* __restrict__ src,
                                            int ld, int w, int lane)
{
    #pragma unroll
    for (int p = 0; p < ROWS / 64; ++p) {
        const int rbase = p * 64 + w * 16;
        const int row   = rbase + (lane >> 2);
        const int c16l  = ((lane & 3) - row) & 3;
        const short* g  = src + (long)row * ld + c16l * 8;
        __builtin_amdgcn_global_load_lds(
            (const __attribute__((address_space(1))) void*)g,
            (__attribute__((address_space(3))) void*)&dst[rbase][0],
            16, 0, 0);
    }
}

// ---------------------------------------------------------------------------
struct GemmJob {
    const short* A; const short* B; void* C;
    float alpha;
    int lda, ldb, ldc, K, inner, gx, gy, Z, splitH, cfg, blkBase, pad0;
    long sA, sB, zAh, zAg, zBh, zBg, zCh, zCg;
};
struct GemmJobs { GemmJob j[8]; int njobs; };

// ---- legacy 128^2 GEMM body (verified): C = alpha * sum_ib A[M,K] @ B[Nc,K]^T
template<int TM, int TN, typename TC>
__device__ __forceinline__ void gemm_body(const GemmJob& job, int lb,
                                          short (*As)[32], short (*Bs)[32])
{
    constexpr int MT = TM / 32;
    constexpr int NT = TN / 32;
    const short* A = job.A;
    const short* B = job.B;
    TC* C = (TC*)job.C;
    const int bps = job.gx * job.gy;
    const int Z   = job.Z;
    int z, r;
    if ((Z & 7) == 0) {
        const int xcd = lb & 7;
        const int j   = lb >> 3;
        const int spx = Z >> 3;
        z = xcd * spx + j / bps;
        r = j % bps;
    } else {
        z = lb / bps;
        r = lb % bps;
    }
    const int x = r % job.gx, y = r / job.gx;
    int h, g;
    if (job.splitH) { h = z & (HH - 1); g = z >> 2; }
    else            { h = 0;            g = z;      }
    A += (long)h * job.zAh + (long)g * job.zAg;
    B += (long)h * job.zBh + (long)g * job.zBg;
    C += (long)h * job.zCh + (long)g * job.zCg;

    const int tid  = threadIdx.x;
    const int lane = tid & 63;
    const int w    = tid >> 6;
    const int wr   = w >> 1;
    const int wc   = w & 1;
    const int quad = lane >> 4;
    const int l16  = lane & 15;
    const long m0  = (long)y * TM;
    const long n0  = (long)x * TN;

    f32x4 acc[MT][NT];
    #pragma unroll
    for (int i = 0; i < MT; ++i)
        #pragma unroll
        for (int j2 = 0; j2 < NT; ++j2)
            acc[i][j2] = (f32x4){0.f, 0.f, 0.f, 0.f};

    for (int ib = 0; ib < job.inner; ++ib) {
        const short* Ab = A + (long)ib * job.sA + m0 * job.lda;
        const short* Bb = B + (long)ib * job.sB + n0 * job.ldb;
        for (int k0 = 0; k0 < job.K; k0 += 32) {
            stage_async<TM>(As, Ab + k0, job.lda, w, lane);
            stage_async<TN>(Bs, Bb + k0, job.ldb, w, lane);
            __syncthreads();
            short8 af[MT], bfr[NT];
            #pragma unroll
            for (int i = 0; i < MT; ++i) {
                const int rowA = wr * (TM / 2) + i * 16 + l16;
                af[i] = *(const short8*)&As[rowA][((quad + rowA) & 3) * 8];
            }
            #pragma unroll
            for (int j2 = 0; j2 < NT; ++j2) {
                const int rowB = wc * (TN / 2) + j2 * 16 + l16;
                bfr[j2] = *(const short8*)&Bs[rowB][((quad + rowB) & 3) * 8];
            }
            #pragma unroll
            for (int i = 0; i < MT; ++i)
                #pragma unroll
                for (int j2 = 0; j2 < NT; ++j2)
                    acc[i][j2] = __builtin_amdgcn_mfma_f32_16x16x32_bf16(
                        af[i], bfr[j2], acc[i][j2], 0, 0, 0);
            __syncthreads();
        }
    }

    #pragma unroll
    for (int i = 0; i < MT; ++i) {
        #pragma unroll
        for (int j2 = 0; j2 < NT; ++j2) {
            const long row = m0 + wr * (TM / 2) + i * 16 + quad * 4;
            const long col = n0 + wc * (TN / 2) + j2 * 16 + l16;
            #pragma unroll
            for (int rr = 0; rr < 4; ++rr) {
                const float v = job.alpha * acc[i][j2][rr];
                if constexpr (sizeof(TC) == 4)
                    C[(row + rr) * job.ldc + col] = v;
                else
                    C[(row + rr) * job.ldc + col] = f2bf(v);
            }
        }
    }
}

template<typename TC>
__global__ __launch_bounds__(256) void mfma_jt(GemmJobs J)
{
    __shared__ short As[128][32];
    __shared__ short Bs[128][32];
    const int bid = blockIdx.x;
    int ji = 0;
    while (ji + 1 < J.njobs && bid >= J.j[ji + 1].blkBase) ++ji;
    const GemmJob& job = J.j[ji];
    const int lb = bid - job.blkBase;
    switch (job.cfg) {
        case 0: gemm_body<128, 128, TC>(job, lb, As, Bs); break;
        case 1: gemm_body<128,  64, TC>(job, lb, As, Bs); break;
        default: gemm_body<64, 128, TC>(job, lb, As, Bs); break;
    }
}

// ---------------------------------------------------------------------------
// 256^2-tile, BK=64, 8-wave, 8-phase bf16 NT GEMM, counted vmcnt.
// Round-5 change (unmeasured last round due to broker timeout — resubmitted):
// B panel read ONCE per K-tile (8 ds_read_b128 -> bfall_), A per half (8+8).
// Per-tile ds_reads 32 -> 24 (the m201 minimum); phases 2 and 4 are zero-read
// (lgkmcnt(0) free). Staging cadence and vmcnt(4) discipline identical to the
// verified round-4 schedule:
//   ph1 stages (t+1)A1, ph2 (t+1)B1, ph3 (t+2)A0, ph4 (t+2)B0 + vmcnt(4).
// Overwrite safety: every staged region's last reader is ph1 (B, A-half0) or
// ph3 (A-half1) of an earlier-or-current tile, always >=2 barriers before the
// re-stage issue.
// ---------------------------------------------------------------------------
#define STAGE(Pa, Pb, DST) do {                                                  \
    __builtin_amdgcn_global_load_lds(                                            \
        (const __attribute__((address_space(1))) void*)(Pa),                     \
        (__attribute__((address_space(3))) void*)(DST), 16, 0, 0);               \
    __builtin_amdgcn_global_load_lds(                                            \
        (const __attribute__((address_space(1))) void*)(Pb),                     \
        (__attribute__((address_space(3))) void*)((DST) + 4096), 16, 0, 0);      \
    (Pa) += 64; (Pb) += 64;                                                      \
} while (0)

// barrier + drain + one C-quadrant (16 MFMA) using cached af_/bfall_
#define BARRQ(AA, BB) do {                                                       \
    __builtin_amdgcn_s_barrier();                                                \
    asm volatile("s_waitcnt lgkmcnt(0)" ::: "memory");                           \
    __builtin_amdgcn_sched_barrier(0);                                           \
    __builtin_amdgcn_s_setprio(1);                                               \
    _Pragma("unroll")                                                            \
    for (int mi_ = 0; mi_ < 4; ++mi_)                                            \
        _Pragma("unroll")                                                        \
        for (int nj_ = 0; nj_ < 2; ++nj_) {                                      \
            acc[(AA)*4 + mi_][(BB)*2 + nj_] = __builtin_amdgcn_mfma_f32_16x16x32_bf16( \
                af_[mi_][0], bfall_[(BB)*2 + nj_][0],                            \
                acc[(AA)*4 + mi_][(BB)*2 + nj_], 0, 0, 0);                       \
            acc[(AA)*4 + mi_][(BB)*2 + nj_] = __builtin_amdgcn_mfma_f32_16x16x32_bf16( \
                af_[mi_][1], bfall_[(BB)*2 + nj_][1],                            \
                acc[(AA)*4 + mi_][(BB)*2 + nj_], 0, 0, 0);                       \
        }                                                                        \
    __builtin_amdgcn_s_setprio(0);                                               \
    __builtin_amdgcn_s_barrier();                                                \
} while (0)

#define TILE(Q, T) do {                                                          \
    short8 af_[4][2], bfall_[4][2];                                              \
    /* ph1: read A-half0 (8) + ALL B (8); stage (t+1)A1 */                       \
    _Pragma("unroll")                                                            \
    for (int mi_ = 0; mi_ < 4; ++mi_)                                            \
        _Pragma("unroll")                                                        \
        for (int ks_ = 0; ks_ < 2; ++ks_)                                        \
            af_[mi_][ks_] = *(const short8*)(paf0[mi_][ks_] + (Q)*16384);        \
    _Pragma("unroll")                                                            \
    for (int nj_ = 0; nj_ < 4; ++nj_)                                            \
        _Pragma("unroll")                                                        \
        for (int ks_ = 0; ks_ < 2; ++ks_)                                        \
            bfall_[nj_][ks_] = *(const short8*)(pbf0[nj_][ks_] + (Q)*16384);     \
    if ((T) + 1 < NT) STAGE(gA1a, gA1b, &AT[1-(Q)][1][0][0] + dofs);             \
    asm volatile("s_waitcnt lgkmcnt(8)" ::: "memory");                           \
    BARRQ(0, 0);                                                                 \
    /* ph2: zero reads; stage (t+1)B1 */                                         \
    if ((T) + 1 < NT) STAGE(gB1a, gB1b, &BT[1-(Q)][1][0][0] + dofs);             \
    BARRQ(0, 1);                                                                 \
    /* ph3: read A-half1 (8); stage (t+2)A0 */                                   \
    _Pragma("unroll")                                                            \
    for (int mi_ = 0; mi_ < 4; ++mi_)                                            \
        _Pragma("unroll")                                                        \
        for (int ks_ = 0; ks_ < 2; ++ks_)                                        \
            af_[mi_][ks_] = *(const short8*)(paf0[mi_][ks_] + (Q)*16384 + 8192); \
    if ((T) + 2 < NT) STAGE(gA0a, gA0b, &AT[(Q)][0][0][0] + dofs);               \
    BARRQ(1, 0);                                                                 \
    /* ph4: zero reads; stage (t+2)B0 + counted vmcnt */                         \
    if ((T) + 2 < NT) {                                                          \
        STAGE(gB0a, gB0b, &BT[(Q)][0][0][0] + dofs);                             \
        asm volatile("s_waitcnt vmcnt(4)" ::: "memory");                         \
    } else {                                                                     \
        asm volatile("s_waitcnt vmcnt(0)" ::: "memory");                         \
    }                                                                            \
    BARRQ(1, 1);                                                                 \
} while (0)

template<typename TC, int STATS>
__global__ __launch_bounds__(512, 2) void mfma8(GemmJobs J, float* __restrict__ statsAcc)
{
    __shared__ short AT[2][2][128][64];
    __shared__ short BT[2][2][128][64];

    const int bid = blockIdx.x;
    int ji = 0;
    while (ji + 1 < J.njobs && bid >= J.j[ji + 1].blkBase) ++ji;
    const GemmJob& job = J.j[ji];
    const int lb = bid - job.blkBase;
    const int Z  = job.Z;
    const int gx = job.gx;
    const int bps = gx * job.gy;
    int z, r;
    if ((Z & 7) == 0) {
        const int xcd = lb & 7;
        const int jj  = lb >> 3;
        const int spx = Z >> 3;
        z = xcd * spx + jj / bps;
        r = jj % bps;
    } else {
        z = lb / bps;
        r = lb % bps;
    }
    const int x = r % gx, y = r / gx;
    int h, g;
    if (job.splitH) { h = z & (HH - 1); g = z >> 2; }
    else            { h = 0;            g = z;      }
    const int lda = job.lda, ldb = job.ldb, ldc = job.ldc;
    const short* A = job.A + (long)h * job.zAh + (long)g * job.zAg + (long)(y * 256) * lda;
    const short* B = job.B + (long)h * job.zBh + (long)g * job.zBg + (long)(x * 256) * ldb;
    TC* C = (TC*)job.C + (long)h * job.zCh + (long)g * job.zCg;
    const int NT = job.K >> 6;

    const int tid  = threadIdx.x;
    const int lane = tid & 63;
    const int w    = tid >> 6;
    const int wm   = w >> 2;        // 0..1
    const int wn   = w & 3;         // 0..3
    const int quad = lane >> 4;
    const int l16  = lane & 15;
    const int dofs = w * 512;       // LDS short-offset of this wave's 1KB stage slot

    // global stage pointers (per-lane, chunk-rotation pre-swizzled [m104/m173])
    const int o16 = w * 64 + lane;
    const int rS  = o16 >> 3;
    const int pcS = o16 & 7;
    const int lcS = ((pcS - rS) & 7) * 8;
    const short* gA0a = A + (long)rS * lda + lcS;
    const short* gA0b = A + (long)(rS + 64) * lda + lcS;
    const short* gA1a = gA0a + 128 * lda;
    const short* gA1b = gA0b + 128 * lda;
    const short* gB0a = B + (long)rS * ldb + lcS;
    const short* gB0b = B + (long)(rS + 64) * ldb + lcS;
    const short* gB1a = gB0a + 128 * ldb;
    const short* gB1b = gB0b + 128 * ldb;

    // hoisted LDS fragment base addresses (q=0; A at half0, B covers both halves)
    const short* paf0[4][2];
    #pragma unroll
    for (int mi = 0; mi < 4; ++mi)
        #pragma unroll
        for (int ks = 0; ks < 2; ++ks) {
            const int rr = mi * 32 + wm * 16 + l16;
            paf0[mi][ks] = &AT[0][0][rr][((ks * 4 + quad + rr) & 7) * 8];
        }
    const short* pbf0[4][2];
    #pragma unroll
    for (int nj = 0; nj < 4; ++nj)
        #pragma unroll
        for (int ks = 0; ks < 2; ++ks) {
            const int r2 = (nj & 1) * 64 + wn * 16 + l16;
            pbf0[nj][ks] = &BT[0][nj >> 1][r2][((ks * 4 + quad + r2) & 7) * 8];
        }

    f32x4 acc[8][4];
    #pragma unroll
    for (int i = 0; i < 8; ++i)
        #pragma unroll
        for (int j2 = 0; j2 < 4; ++j2)
            acc[i][j2] = (f32x4){0.f, 0.f, 0.f, 0.f};

    // prologue: tile0 all 4 halves + tile1 A0/B0; drain tile0, keep tile1 in flight
    STAGE(gA0a, gA0b, &AT[0][0][0][0] + dofs);
    STAGE(gA1a, gA1b, &AT[0][1][0][0] + dofs);
    STAGE(gB0a, gB0b, &BT[0][0][0][0] + dofs);
    STAGE(gB1a, gB1b, &BT[0][1][0][0] + dofs);
    STAGE(gA0a, gA0b, &AT[1][0][0][0] + dofs);   // NT >= 4 in all uses
    STAGE(gB0a, gB0b, &BT[1][0][0][0] + dofs);
    asm volatile("s_waitcnt vmcnt(4)" ::: "memory");
    __builtin_amdgcn_s_barrier();

    const int NPAIR = NT >> 1;
    for (int tt = 0; tt < NPAIR; ++tt) {
        TILE(0, tt * 2);
        TILE(1, tt * 2 + 1);
    }
    if (NT & 1) TILE(0, NT - 1);

    // epilogue: C/D layout col=lane&15, row=(lane>>4)*4+reg [m89-verified]
    float s0 = 0.f, ss0 = 0.f, s1 = 0.f, ss1 = 0.f;   // buckets: rows<896, rows 896..959
    #pragma unroll
    for (int mi = 0; mi < 8; ++mi) {
        #pragma unroll
        for (int nj = 0; nj < 4; ++nj) {
            const long row = (long)y * 256 + mi * 32 + wm * 16 + quad * 4;
            const long col = (long)x * 256 + nj * 64 + wn * 16 + l16;
            #pragma unroll
            for (int rr = 0; rr < 4; ++rr) {
                const float v = job.alpha * acc[mi][nj][rr];
                if constexpr (sizeof(TC) == 4)
                    C[(row + rr) * ldc + col] = v;
                else
                    C[(row + rr) * ldc + col] = f2bf(v);
                if constexpr (STATS) {
                    const long gr = row + rr;
                    if (gr < 896)          { s0 += v; ss0 += v * v; }
                    else if (gr < KVD)     { s1 += v; ss1 += v * v; }
                }
            }
        }
    }
    if constexpr (STATS) {
        __syncthreads();
        float* red = (float*)&AT[0][0][0][0];
        red[tid] = s0; red[512 + tid] = ss0; red[1024 + tid] = s1; red[1536 + tid] = ss1;
        __syncthreads();
        for (int o = 256; o > 0; o >>= 1) {
            if (tid < o) {
                red[tid]        += red[tid + o];
                red[512 + tid]  += red[512 + tid + o];
                red[1024 + tid] += red[1024 + tid + o];
                red[1536 + tid] += red[1536 + tid + o];
            }
            __syncthreads();
        }
        if (tid == 0) {
            const int m0g = y * 256;
            const int bA = (m0g >= 768) ? 1 : (m0g >= 512) ? 2 : 3;
            atomicAdd(&statsAcc[((long)z * 4 + bA) * 2],     red[0]);
            atomicAdd(&statsAcc[((long)z * 4 + bA) * 2 + 1], red[512]);
            if (y == 3) {   // rows 896..959 -> branch 0 (df=64)
                atomicAdd(&statsAcc[((long)z * 4 + 0) * 2],     red[1024]);
                atomicAdd(&statsAcc[((long)z * 4 + 0) * 2 + 1], red[1536]);
            }
        }
    }
}

// ---- softmax over real 960 cols; stats finalize inlined (reads atomic sums).
__global__ void softmax_kernel(const float* __restrict__ S,
                               short* __restrict__ Sa,
                               const float* __restrict__ acc)
{
    const int row = blockIdx.x;          // 0..1023 concat rows (>=960 = pad)
    const int y   = blockIdx.y;
    const int t   = threadIdx.x;
    short* orow = Sa + ((long)y * ECAT + row) * KVP;
    if (row >= KVD) {                    // zero pad row (clean B-operand for Ch)
        *(short4e*)(orow + 4 * t) = (short4e){0, 0, 0, 0};
        return;
    }
    const int bidx = (row >= 896) ? 0 : (row >= 768) ? 1 : (row >= 512) ? 2 : 3;
    const int dftab[4] = {64, 128, 256, 512};
    const float sum0 = acc[((long)y * 4 + bidx) * 2];
    const float ssq0 = acc[((long)y * 4 + bidx) * 2 + 1];
    const float n    = (float)(dftab[bidx] * KVD);
    const float mean = sum0 / n;
    const float rstd = rsqrtf(ssq0 / n - mean * mean + EPS);
    const float* srow = S + ((long)y * ECAT + row) * KVP;

    const bool real = (t < KVD / 4);     // threads 0..239 hold real cols (4 each)
    float x[4];
    float mx = -1e30f;
    if (real) {
        const float4 v = *(const float4*)(srow + 4 * t);
        x[0] = (v.x - mean) * rstd; x[1] = (v.y - mean) * rstd;
        x[2] = (v.z - mean) * rstd; x[3] = (v.w - mean) * rstd;
        mx = fmaxf(fmaxf(x[0], x[1]), fmaxf(x[2], x[3]));
    }
    __shared__ float red[256];
    red[t] = mx; __syncthreads();
    for (int o = 128; o > 0; o >>= 1) {
        if (t < o) red[t] = fmaxf(red[t], red[t + o]);
        __syncthreads();
    }
    mx = red[0];
    __syncthreads();

    float e[4] = {0.f, 0.f, 0.f, 0.f};
    float sum = 0.f;
    if (real) {
        e[0] = __expf(x[0] - mx); e[1] = __expf(x[1] - mx);
        e[2] = __expf(x[2] - mx); e[3] = __expf(x[3] - mx);
        sum = e[0] + e[1] + e[2] + e[3];
    }
    red[t] = sum; __syncthreads();
    for (int o = 128; o > 0; o >>= 1) {
        if (t < o) red[t] += red[t + o];
        __syncthreads();
    }
    const float inv = 1.0f / red[0];
    short4e o4;
    o4[0] = f2bf(e[0] * inv); o4[1] = f2bf(e[1] * inv);
    o4[2] = f2bf(e[2] * inv); o4[3] = f2bf(e[3] * inv);
    *(short4e*)(orow + 4 * t) = o4;
}

// ---------------------------------------------------------------------------
extern "C" void kernel_launch(void* const* d_in, const int* in_sizes, int n_in,
                              void* d_out, int out_size, void* d_ws, size_t ws_size,
                              hipStream_t stream)
{
    (void)in_sizes; (void)n_in; (void)out_size;
    const float* emb[4]  = {(const float*)d_in[0], (const float*)d_in[1],
                            (const float*)d_in[2], (const float*)d_in[3]};
    const float* emb_all = (const float*)d_in[4];
    const float* WQ[4]   = {(const float*)d_in[5], (const float*)d_in[6],
                            (const float*)d_in[7], (const float*)d_in[8]};
    const float* WK      = (const float*)d_in[9];
    const float* WV      = (const float*)d_in[10];
    const float* WO[4]   = {(const float*)d_in[11], (const float*)d_in[12],
                            (const float*)d_in[13], (const float*)d_in[14]};
    float* out = (float*)d_out;

    const int dfs[4]    = {64, 128, 256, 512};
    const int rowoff[4] = {896, 768, 512, 0};   // concat offsets (tile-aligned)
    const long N = NSEQ;

    // ---- workspace budget (Sacat aliases KT+Qcat; Chcat aliases Scat)
    const long eAll = (long)BATCH * N * KVD;
    const long eWKp = (long)HH * KVP * KVD;
    long preBytes = eAll * 2 + 2 * eWKp * 2;
    for (int br = 0; br < 4; ++br)
        preBytes += ((long)BATCH * N * dfs[br] + (long)HH * dfs[br] * dfs[br]
                    + (long)dfs[br] * dfs[br]) * 2;
    const long perG = (long)HH * KVP * N * 2
                    + (long)HH * ECAT * N * 2
                    + (long)HH * N * KVP * 2
                    + (long)HH * ECAT * KVP * 4;
    int G = 8;
    while (G > 1 && preBytes + (long)G * perG + 65536 > (long)ws_size) G >>= 1;

    // ---- carve workspace (KTb and Qb contiguous: Sab aliases their union)
    char* p = (char*)d_ws;
    short* embAllp = (short*)p; p += eAll * 2;
    short* embp[4]; short* WQp[4]; short* WOp[4];
    for (int br = 0; br < 4; ++br) { embp[br] = (short*)p; p += (long)BATCH * N * dfs[br] * 2; }
    for (int br = 0; br < 4; ++br) { WQp[br]  = (short*)p; p += (long)HH * dfs[br] * dfs[br] * 2; }
    short* WKp = (short*)p; p += eWKp * 2;
    short* WVp = (short*)p; p += eWKp * 2;
    for (int br = 0; br < 4; ++br) { WOp[br]  = (short*)p; p += (long)dfs[br] * dfs[br] * 2; }
    short* KTb = (short*)p; p += (long)G * HH * KVP * N * 2;
    short* Qb  = (short*)p; p += (long)G * HH * ECAT * N * 2;    // Qcat
    short* Vb  = (short*)p; p += (long)G * HH * N * KVP * 2;
    float* Sb  = (float*)p; p += (long)G * HH * ECAT * KVP * 4;  // Scat
    float* statsAcc = (float*)p; p += (long)BATCH * HH * 4 * 2 * 4;
    short* Sab = (short*)KTb;  // Sacat aliases KT+Qcat (dead after S GEMM)
    short* Chb = (short*)Sb;   // Chcat aliases Scat (dead after softmax)

    // ---- ONE convert launch: 13 plain segments + 2 padded-W segments
    {
        ConvJobs J;
        long cum = 0; int sg = 0;
        auto addJob = [&](const float* src, short* dst, long nunits, int ty) {
            J.src[sg] = src; J.dst[sg] = dst; J.cum[sg] = cum; J.type[sg] = ty;
            cum += nunits; ++sg;
        };
        addJob(emb_all, embAllp, eAll / 8, 0);
        for (int br = 0; br < 4; ++br) addJob(emb[br], embp[br], (long)BATCH * N * dfs[br] / 8, 0);
        for (int br = 0; br < 4; ++br) addJob(WQ[br], WQp[br], (long)HH * dfs[br] * dfs[br] / 8, 0);
        for (int br = 0; br < 4; ++br) addJob(WO[br], WOp[br], (long)dfs[br] * dfs[br] / 8, 0);
        addJob(WK, WKp, (long)HH * KVP * (KVD / 8), 1);
        addJob(WV, WVp, (long)HH * KVP * (KVD / 8), 1);
        J.cum[15] = cum;
        J.statsAcc = statsAcc;
        J.nAcc = BATCH * HH * 4 * 2;
        conv_all_kernel<<<dim3((unsigned)((cum + 255) / 256)), dim3(256), 0, stream>>>(J);
    }

    const float scale = 1.0f / sqrtf((float)KVD);
    long outBase[4];
    {
        long acc = 0;
        for (int br = 0; br < 4; ++br) { outBase[br] = acc; acc += (long)BATCH * N * dfs[br]; }
    }

    const dim3 blk(256), blk8(512);
    int it = 0;
    for (int b0 = 0; b0 < BATCH; b0 += G, ++it) {
        const int Z = G * HH;
        const short* embA = embAllp + (long)b0 * N * KVD;
        float* accIt = statsAcc + (long)it * Z * 4 * 2;

        // ---- mega1 on mfma8: KT + V + Q512 + Q256 (one job table) -------------
        {
            GemmJobs J; int nj = 0; int base = 0;
            auto add8 = [&](const short* A, const short* B, void* C, float alpha,
                            int lda, int ldb, int ldc, int K,
                            long zAh, long zAg, long zBh, long zBg,
                            long zCh, long zCg, int gx, int gy) {
                GemmJob& q = J.j[nj];
                q.A = A; q.B = B; q.C = C; q.alpha = alpha;
                q.lda = lda; q.ldb = ldb; q.ldc = ldc; q.K = K; q.inner = 1;
                q.sA = 0; q.sB = 0;
                q.zAh = zAh; q.zAg = zAg; q.zBh = zBh; q.zBg = zBg;
                q.zCh = zCh; q.zCg = zCg;
                q.splitH = 1; q.gx = gx; q.gy = gy; q.Z = Z; q.cfg = 0;
                q.blkBase = base;
                base += gx * gy * Z; ++nj;
            };
            // KT[g][h][j(1024)][n] = sum_k WKp[h][j][k] embA[g][n][k]
            add8(WKp, embA, KTb, 1.0f, KVD, KVD, (int)N, KVD,
                 (long)KVP * KVD, 0, 0, (long)N * KVD,
                 (long)KVP * N, (long)HH * KVP * N, 4, 4);
            // V[g][h][n][j(1024)] = sum_k embA[g][n][k] WVp[h][j][k]
            add8(embA, WVp, Vb, 1.0f, KVD, KVD, KVP, KVD,
                 0, (long)N * KVD, (long)KVP * KVD, 0,
                 (long)N * KVP, (long)HH * N * KVP, 4, 4);
            // Q512: M=512 (gy=2) -> concat rows 0..511
            add8(WQp[3], embp[3] + (long)b0 * N * 512, Qb + (long)rowoff[3] * N, 1.0f,
                 512, 512, (int)N, 512,
                 512L * 512, 0, 0, (long)N * 512,
                 (long)ECAT * N, (long)HH * ECAT * N, 4, 2);
            // Q256: M=256 (gy=1) -> concat rows 512..767
            add8(WQp[2], embp[2] + (long)b0 * N * 256, Qb + (long)rowoff[2] * N, 1.0f,
                 256, 256, (int)N, 256,
                 256L * 256, 0, 0, (long)N * 256,
                 (long)ECAT * N, (long)HH * ECAT * N, 4, 1);
            J.njobs = nj;
            mfma8<short, 0><<<dim3(base), blk8, 0, stream>>>(J, nullptr);
        }

        // ---- Q128 + Q64 (legacy job-table) -> concat rows of Qcat -------------
        {
            GemmJobs J; int nj = 0; int base = 0;
            for (int br = 1; br >= 0; --br) {
                const int df = dfs[br];
                const short* embB = embp[br] + (long)b0 * N * df;
                short* Qdst = Qb + (long)rowoff[br] * N;
                GemmJob& q = J.j[nj];
                q.A = WQp[br]; q.B = embB; q.C = Qdst; q.alpha = 1.0f;
                q.lda = df; q.ldb = df; q.ldc = (int)N; q.K = df; q.inner = 1;
                q.sA = 0; q.sB = 0;
                q.zAh = (long)df * df; q.zAg = 0;
                q.zBh = 0;             q.zBg = (long)N * df;
                q.zCh = (long)ECAT * N; q.zCg = (long)HH * ECAT * N;
                q.splitH = 1; q.Z = Z; q.gx = 8; q.gy = 1;
                q.cfg = (df >= 128) ? 0 : 2;
                q.blkBase = base;
                base += 8 * Z;
                ++nj;
            }
            J.njobs = nj;
            mfma_jt<short><<<dim3(base), blk, 0, stream>>>(J);
        }

        // ---- S on mfma8 (fused instance-norm stats) ---------------------------
        {
            GemmJobs J; J.njobs = 1;
            GemmJob& s = J.j[0];
            s.A = Qb; s.B = KTb; s.C = Sb; s.alpha = scale;
            s.lda = (int)N; s.ldb = (int)N; s.ldc = KVP; s.K = (int)N; s.inner = 1;
            s.sA = 0; s.sB = 0;
            s.zAh = (long)ECAT * N;  s.zAg = (long)HH * ECAT * N;
            s.zBh = (long)KVP * N;   s.zBg = (long)HH * KVP * N;
            s.zCh = (long)ECAT * KVP; s.zCg = (long)HH * ECAT * KVP;
            s.splitH = 1; s.gx = 4; s.gy = 4; s.Z = Z; s.cfg = 0; s.blkBase = 0;
            mfma8<float, 1><<<dim3(16 * Z), blk8, 0, stream>>>(J, accIt);
        }

        // softmax (stats finalize inlined); writes Sab over dead KT+Qcat
        softmax_kernel<<<dim3(ECAT, Z), dim3(256), 0, stream>>>(Sb, Sab, accIt);

        // ---- Ch on mfma8 ------------------------------------------------------
        {
            GemmJobs J; J.njobs = 1;
            GemmJob& c = J.j[0];
            c.A = Vb; c.B = Sab; c.C = Chb; c.alpha = 1.0f;
            c.lda = KVP; c.ldb = KVP; c.ldc = ECAT; c.K = KVP; c.inner = 1;
            c.sA = 0; c.sB = 0;
            c.zAh = (long)N * KVP;   c.zAg = (long)HH * N * KVP;
            c.zBh = (long)ECAT * KVP; c.zBg = (long)HH * ECAT * KVP;
            c.zCh = (long)N * ECAT;  c.zCg = (long)HH * N * ECAT;
            c.splitH = 1; c.gx = 4; c.gy = 4; c.Z = Z; c.cfg = 0; c.blkBase = 0;
            mfma8<short, 0><<<dim3(16 * Z), blk8, 0, stream>>>(J, nullptr);
        }

        // ---- O mega-launch: 4 branches, one job table (legacy) ----------------
        {
            GemmJobs J; int nj = 0; int base = 0;
            for (int br = 3; br >= 0; --br) {
                const int df = dfs[br];
                const short* Asrc = Chb + rowoff[br];
                float* Cout = out + outBase[br] + (long)b0 * N * df;
                GemmJob& q = J.j[nj];
                q.A = Asrc; q.B = WOp[br]; q.C = Cout; q.alpha = 1.0f / HH;
                q.lda = ECAT; q.ldb = df; q.ldc = df; q.K = df; q.inner = HH;
                q.sA = (long)N * ECAT; q.sB = 0;
                q.zAh = 0; q.zAg = (long)HH * N * ECAT; q.zBh = 0; q.zBg = 0;
                q.zCh = 0; q.zCg = (long)N * df;
                q.splitH = 0; q.Z = G; q.gy = 8;
                if (df >= 128) { q.cfg = 0; q.gx = df / 128; }
                else           { q.cfg = 1; q.gx = 1;        }
                q.blkBase = base;
                base += q.gx * q.gy * G;
                ++nj;
            }
            J.njobs = nj;
            mfma_jt<float><<<dim3(base), blk, 0, stream>>>(J);
        }
    }
}

// Round 7
// 621.041 us; speedup vs baseline: 1.7787x; 1.0122x over previous
//
#include <hip/hip_runtime.h>
#include <hip/hip_bf16.h>
#include <math.h>

#define HH    4
#define NSEQ  1024
#define KVD   960    // true KV dim
#define KVP   1024   // padded KV dim (zero pad) so every tile dim is 128-divisible
#define BATCH 8
#define ECAT  1024   // concat of branch channel dims (960 real, 64 pad rows)

static constexpr float EPS = 1e-5f;

typedef __attribute__((ext_vector_type(8))) short short8;   // 8 bf16
typedef __attribute__((ext_vector_type(4))) short short4e;  // 4 bf16
typedef __attribute__((ext_vector_type(4))) float f32x4;    // MFMA C/D frag

__device__ __forceinline__ short f2bf(float x) {
    union { __hip_bfloat16 h; short s; } u;
    u.h = __float2bfloat16(x);
    return u.s;
}
__device__ __forceinline__ short8 cvt8(const float* __restrict__ g) {
    const float4 a = *(const float4*)g;
    const float4 b = *(const float4*)(g + 4);
    short8 t;
    t[0] = f2bf(a.x); t[1] = f2bf(a.y); t[2] = f2bf(a.z); t[3] = f2bf(a.w);
    t[4] = f2bf(b.x); t[5] = f2bf(b.y); t[6] = f2bf(b.z); t[7] = f2bf(b.w);
    return t;
}

// ---- one-time input converts: 15 segments (13 plain + 2 padded-W) in ONE launch
struct ConvJobs {
    const float* src[15];
    short*       dst[15];
    long         cum[16];
    int          type[15];   // 0 = plain copy, 1 = padded WK/WV layout
    float*       statsAcc;   // zero-init side effect (block 0)
    int          nAcc;
};

__global__ void conv_all_kernel(ConvJobs J)
{
    if (blockIdx.x == 0 && threadIdx.x < (unsigned)J.nAcc)
        J.statsAcc[threadIdx.x] = 0.f;
    const long u = (long)blockIdx.x * 256 + threadIdx.x;
    if (u >= J.cum[15]) return;
    int sg = 0;
    while (u >= J.cum[sg + 1]) ++sg;
    const long l = u - J.cum[sg];
    if (J.type[sg] == 0) {
        *(short8*)(J.dst[sg] + l * 8) = cvt8(J.src[sg] + l * 8);
    } else {
        const int cpr = KVD / 8;                              // 120
        const int c8  = (int)(l % cpr) * 8;
        const int row = (int)((l / cpr) % KVP);
        const int h   = (int)(l / ((long)cpr * KVP));
        short8 t = (short8){0,0,0,0,0,0,0,0};
        if (row < KVD) t = cvt8(J.src[sg] + ((long)h * KVD + row) * KVD + c8);
        *(short8*)(J.dst[sg] + ((long)h * KVP + row) * KVD + c8) = t;
    }
}

// ---- legacy async LDS staging: ROWS x 32 bf16, 64B rows, chunk-XOR swizzle.
template<int ROWS>
__device__ __forceinline__ void stage_async(short (*dst)[32], const short* __restrict__ src,
                                            int ld, int w, int lane)
{
    #pragma unroll
    for (int p = 0; p < ROWS / 64; ++p) {
        const int rbase = p * 64 + w * 16;
        const int row   = rbase + (lane >> 2);
        const int c16l  = ((lane & 3) - row) & 3;
        const short* g  = src + (long)row * ld + c16l * 8;
        __builtin_amdgcn_global_load_lds(
            (const __attribute__((address_space(1))) void*)g,
            (__attribute__((address_space(3))) void*)&dst[rbase][0],
            16, 0, 0);
    }
}

// ---------------------------------------------------------------------------
struct GemmJob {
    const short* A; const short* B; void* C;
    float alpha;
    int lda, ldb, ldc, K, inner, gx, gy, Z, splitH, cfg, blkBase, pad0;
    long sA, sB, zAh, zAg, zBh, zBg, zCh, zCg;
};
struct GemmJobs { GemmJob j[8]; int njobs; };

// ---- legacy 128^2 GEMM body (verified): C = alpha * sum_ib A[M,K] @ B[Nc,K]^T
template<int TM, int TN, typename TC>
__device__ __forceinline__ void gemm_body(const GemmJob& job, int lb,
                                          short (*As)[32], short (*Bs)[32])
{
    constexpr int MT = TM / 32;
    constexpr int NT = TN / 32;
    const short* A = job.A;
    const short* B = job.B;
    TC* C = (TC*)job.C;
    const int bps = job.gx * job.gy;
    const int Z   = job.Z;
    int z, r;
    if ((Z & 7) == 0) {
        const int xcd = lb & 7;
        const int j   = lb >> 3;
        const int spx = Z >> 3;
        z = xcd * spx + j / bps;
        r = j % bps;
    } else {
        z = lb / bps;
        r = lb % bps;
    }
    const int x = r % job.gx, y = r / job.gx;
    int h, g;
    if (job.splitH) { h = z & (HH - 1); g = z >> 2; }
    else            { h = 0;            g = z;      }
    A += (long)h * job.zAh + (long)g * job.zAg;
    B += (long)h * job.zBh + (long)g * job.zBg;
    C += (long)h * job.zCh + (long)g * job.zCg;

    const int tid  = threadIdx.x;
    const int lane = tid & 63;
    const int w    = tid >> 6;
    const int wr   = w >> 1;
    const int wc   = w & 1;
    const int quad = lane >> 4;
    const int l16  = lane & 15;
    const long m0  = (long)y * TM;
    const long n0  = (long)x * TN;

    f32x4 acc[MT][NT];
    #pragma unroll
    for (int i = 0; i < MT; ++i)
        #pragma unroll
        for (int j2 = 0; j2 < NT; ++j2)
            acc[i][j2] = (f32x4){0.f, 0.f, 0.f, 0.f};

    for (int ib = 0; ib < job.inner; ++ib) {
        const short* Ab = A + (long)ib * job.sA + m0 * job.lda;
        const short* Bb = B + (long)ib * job.sB + n0 * job.ldb;
        for (int k0 = 0; k0 < job.K; k0 += 32) {
            stage_async<TM>(As, Ab + k0, job.lda, w, lane);
            stage_async<TN>(Bs, Bb + k0, job.ldb, w, lane);
            __syncthreads();
            short8 af[MT], bfr[NT];
            #pragma unroll
            for (int i = 0; i < MT; ++i) {
                const int rowA = wr * (TM / 2) + i * 16 + l16;
                af[i] = *(const short8*)&As[rowA][((quad + rowA) & 3) * 8];
            }
            #pragma unroll
            for (int j2 = 0; j2 < NT; ++j2) {
                const int rowB = wc * (TN / 2) + j2 * 16 + l16;
                bfr[j2] = *(const short8*)&Bs[rowB][((quad + rowB) & 3) * 8];
            }
            #pragma unroll
            for (int i = 0; i < MT; ++i)
                #pragma unroll
                for (int j2 = 0; j2 < NT; ++j2)
                    acc[i][j2] = __builtin_amdgcn_mfma_f32_16x16x32_bf16(
                        af[i], bfr[j2], acc[i][j2], 0, 0, 0);
            __syncthreads();
        }
    }

    #pragma unroll
    for (int i = 0; i < MT; ++i) {
        #pragma unroll
        for (int j2 = 0; j2 < NT; ++j2) {
            const long row = m0 + wr * (TM / 2) + i * 16 + quad * 4;
            const long col = n0 + wc * (TN / 2) + j2 * 16 + l16;
            #pragma unroll
            for (int rr = 0; rr < 4; ++rr) {
                const float v = job.alpha * acc[i][j2][rr];
                if constexpr (sizeof(TC) == 4)
                    C[(row + rr) * job.ldc + col] = v;
                else
                    C[(row + rr) * job.ldc + col] = f2bf(v);
            }
        }
    }
}

template<typename TC>
__global__ __launch_bounds__(256) void mfma_jt(GemmJobs J)
{
    __shared__ short As[128][32];
    __shared__ short Bs[128][32];
    const int bid = blockIdx.x;
    int ji = 0;
    while (ji + 1 < J.njobs && bid >= J.j[ji + 1].blkBase) ++ji;
    const GemmJob& job = J.j[ji];
    const int lb = bid - job.blkBase;
    switch (job.cfg) {
        case 0: gemm_body<128, 128, TC>(job, lb, As, Bs); break;
        case 1: gemm_body<128,  64, TC>(job, lb, As, Bs); break;
        default: gemm_body<64, 128, TC>(job, lb, As, Bs); break;
    }
}

// ---------------------------------------------------------------------------
// 256^2-tile, BK=64, 8-wave bf16 NT GEMM, counted vmcnt/lgkmcnt.
// Round-7 restructure: ONE barrier pair per K-tile (was 8 barriers / 4 phases).
// Per tile t (buf q=t&1):
//   issue all 24 ds_read_b128 (order: B x8, A0 x8, A1 x8)
//   stage (t+1)A1,(t+1)B1 -> buf q^1          [their region's readers ended at
//                                              tile t-1's end-barrier]
//   lgkmcnt(8)   -> B + A0 served for THIS wave
//   s_barrier    -> ALL waves served B/A0/B0 reads of buf q
//   stage (t+2)A0,(t+2)B0 -> buf q            [safe: regions fully drained]
//   32 MFMA on (A0,B)  -- A1's 8 reads drain in the shadow of these MFMAs
//   lgkmcnt(0)   (usually free)
//   32 MFMA on (A1,B)
//   vmcnt(4)     -> tile t+1 fully resident; t+2's A0/B0 stay in flight
//   s_barrier    -> publish buf q^1 for tile t+1
// Ledger: enter 4 outstanding; +4 (S1,S2) +4 (S3,S4) = 12; vmcnt(4) drains the
// 8 oldest (= all of tile t+1) keeping 4 (t+2 A0/B0). Never vmcnt(0) mid-loop.
// ---------------------------------------------------------------------------
#define STAGE(Pa, Pb, DST) do {                                                  \
    __builtin_amdgcn_global_load_lds(                                            \
        (const __attribute__((address_space(1))) void*)(Pa),                     \
        (__attribute__((address_space(3))) void*)(DST), 16, 0, 0);               \
    __builtin_amdgcn_global_load_lds(                                            \
        (const __attribute__((address_space(1))) void*)(Pb),                     \
        (__attribute__((address_space(3))) void*)((DST) + 4096), 16, 0, 0);      \
    (Pa) += 64; (Pb) += 64;                                                      \
} while (0)

// 32 MFMA: A-half AF (4 row-tiles) x full B panel (4 col-tiles), K=64
#define MFMAQ(AF, AA)                                                            \
    _Pragma("unroll")                                                            \
    for (int mi_ = 0; mi_ < 4; ++mi_)                                            \
        _Pragma("unroll")                                                        \
        for (int nj_ = 0; nj_ < 4; ++nj_) {                                      \
            acc[(AA)*4 + mi_][nj_] = __builtin_amdgcn_mfma_f32_16x16x32_bf16(    \
                AF[mi_][0], ball_[nj_][0], acc[(AA)*4 + mi_][nj_], 0, 0, 0);     \
            acc[(AA)*4 + mi_][nj_] = __builtin_amdgcn_mfma_f32_16x16x32_bf16(    \
                AF[mi_][1], ball_[nj_][1], acc[(AA)*4 + mi_][nj_], 0, 0, 0);     \
        }

#define TILE(Q, T) do {                                                          \
    short8 af0_[4][2], af1_[4][2], ball_[4][2];                                  \
    _Pragma("unroll")                                                            \
    for (int nj_ = 0; nj_ < 4; ++nj_)                                            \
        _Pragma("unroll")                                                        \
        for (int ks_ = 0; ks_ < 2; ++ks_)                                        \
            ball_[nj_][ks_] = *(const short8*)(pbf0[nj_][ks_] + (Q)*16384);      \
    _Pragma("unroll")                                                            \
    for (int mi_ = 0; mi_ < 4; ++mi_)                                            \
        _Pragma("unroll")                                                        \
        for (int ks_ = 0; ks_ < 2; ++ks_)                                        \
            af0_[mi_][ks_] = *(const short8*)(paf0[mi_][ks_] + (Q)*16384);       \
    _Pragma("unroll")                                                            \
    for (int mi_ = 0; mi_ < 4; ++mi_)                                            \
        _Pragma("unroll")                                                        \
        for (int ks_ = 0; ks_ < 2; ++ks_)                                        \
            af1_[mi_][ks_] = *(const short8*)(paf0[mi_][ks_] + (Q)*16384 + 8192);\
    if ((T) + 1 < NT) {                                                          \
        STAGE(gA1a, gA1b, &AT[1-(Q)][1][0][0] + dofs);                           \
        STAGE(gB1a, gB1b, &BT[1-(Q)][1][0][0] + dofs);                           \
    }                                                                            \
    asm volatile("s_waitcnt lgkmcnt(8)" ::: "memory");                           \
    __builtin_amdgcn_s_barrier();                                                \
    if ((T) + 2 < NT) {                                                          \
        STAGE(gA0a, gA0b, &AT[(Q)][0][0][0] + dofs);                             \
        STAGE(gB0a, gB0b, &BT[(Q)][0][0][0] + dofs);                             \
    }                                                                            \
    __builtin_amdgcn_sched_barrier(0);                                           \
    __builtin_amdgcn_s_setprio(1);                                               \
    MFMAQ(af0_, 0);                                                              \
    __builtin_amdgcn_s_setprio(0);                                               \
    asm volatile("s_waitcnt lgkmcnt(0)" ::: "memory");                           \
    __builtin_amdgcn_sched_barrier(0);                                           \
    __builtin_amdgcn_s_setprio(1);                                               \
    MFMAQ(af1_, 1);                                                              \
    __builtin_amdgcn_s_setprio(0);                                               \
    if ((T) + 2 < NT) asm volatile("s_waitcnt vmcnt(4)" ::: "memory");           \
    else              asm volatile("s_waitcnt vmcnt(0)" ::: "memory");           \
    __builtin_amdgcn_s_barrier();                                                \
} while (0)

template<typename TC, int STATS>
__global__ __launch_bounds__(512, 2) void mfma8(GemmJobs J, float* __restrict__ statsAcc)
{
    __shared__ short AT[2][2][128][64];
    __shared__ short BT[2][2][128][64];

    const int bid = blockIdx.x;
    int ji = 0;
    while (ji + 1 < J.njobs && bid >= J.j[ji + 1].blkBase) ++ji;
    const GemmJob& job = J.j[ji];
    const int lb = bid - job.blkBase;
    const int Z  = job.Z;
    const int gx = job.gx;
    const int bps = gx * job.gy;
    int z, r;
    if ((Z & 7) == 0) {
        const int xcd = lb & 7;
        const int jj  = lb >> 3;
        const int spx = Z >> 3;
        z = xcd * spx + jj / bps;
        r = jj % bps;
    } else {
        z = lb / bps;
        r = lb % bps;
    }
    const int x = r % gx, y = r / gx;
    int h, g;
    if (job.splitH) { h = z & (HH - 1); g = z >> 2; }
    else            { h = 0;            g = z;      }
    const int lda = job.lda, ldb = job.ldb, ldc = job.ldc;
    const short* A = job.A + (long)h * job.zAh + (long)g * job.zAg + (long)(y * 256) * lda;
    const short* B = job.B + (long)h * job.zBh + (long)g * job.zBg + (long)(x * 256) * ldb;
    TC* C = (TC*)job.C + (long)h * job.zCh + (long)g * job.zCg;
    const int NT = job.K >> 6;

    const int tid  = threadIdx.x;
    const int lane = tid & 63;
    const int w    = tid >> 6;
    const int wm   = w >> 2;        // 0..1
    const int wn   = w & 3;         // 0..3
    const int quad = lane >> 4;
    const int l16  = lane & 15;
    const int dofs = w * 512;       // LDS short-offset of this wave's 1KB stage slot

    // global stage pointers (per-lane, chunk-rotation pre-swizzled [m104/m173])
    const int o16 = w * 64 + lane;
    const int rS  = o16 >> 3;
    const int pcS = o16 & 7;
    const int lcS = ((pcS - rS) & 7) * 8;
    const short* gA0a = A + (long)rS * lda + lcS;
    const short* gA0b = A + (long)(rS + 64) * lda + lcS;
    const short* gA1a = gA0a + 128 * lda;
    const short* gA1b = gA0b + 128 * lda;
    const short* gB0a = B + (long)rS * ldb + lcS;
    const short* gB0b = B + (long)(rS + 64) * ldb + lcS;
    const short* gB1a = gB0a + 128 * ldb;
    const short* gB1b = gB0b + 128 * ldb;

    // hoisted LDS fragment base addresses (q=0; A at half0, B covers both halves)
    const short* paf0[4][2];
    #pragma unroll
    for (int mi = 0; mi < 4; ++mi)
        #pragma unroll
        for (int ks = 0; ks < 2; ++ks) {
            const int rr = mi * 32 + wm * 16 + l16;
            paf0[mi][ks] = &AT[0][0][rr][((ks * 4 + quad + rr) & 7) * 8];
        }
    const short* pbf0[4][2];
    #pragma unroll
    for (int nj = 0; nj < 4; ++nj)
        #pragma unroll
        for (int ks = 0; ks < 2; ++ks) {
            const int r2 = (nj & 1) * 64 + wn * 16 + l16;
            pbf0[nj][ks] = &BT[0][nj >> 1][r2][((ks * 4 + quad + r2) & 7) * 8];
        }

    f32x4 acc[8][4];
    #pragma unroll
    for (int i = 0; i < 8; ++i)
        #pragma unroll
        for (int j2 = 0; j2 < 4; ++j2)
            acc[i][j2] = (f32x4){0.f, 0.f, 0.f, 0.f};

    // prologue: tile0 all 4 halves + tile1 A0/B0; drain tile0, keep tile1 in flight
    STAGE(gA0a, gA0b, &AT[0][0][0][0] + dofs);
    STAGE(gA1a, gA1b, &AT[0][1][0][0] + dofs);
    STAGE(gB0a, gB0b, &BT[0][0][0][0] + dofs);
    STAGE(gB1a, gB1b, &BT[0][1][0][0] + dofs);
    STAGE(gA0a, gA0b, &AT[1][0][0][0] + dofs);   // NT >= 4 in all uses
    STAGE(gB0a, gB0b, &BT[1][0][0][0] + dofs);
    asm volatile("s_waitcnt vmcnt(4)" ::: "memory");
    __builtin_amdgcn_s_barrier();

    const int NPAIR = NT >> 1;
    for (int tt = 0; tt < NPAIR; ++tt) {
        TILE(0, tt * 2);
        TILE(1, tt * 2 + 1);
    }
    if (NT & 1) TILE(0, NT - 1);

    // epilogue: C/D layout col=lane&15, row=(lane>>4)*4+reg [m89-verified]
    float s0 = 0.f, ss0 = 0.f, s1 = 0.f, ss1 = 0.f;   // buckets: rows<896, rows 896..959
    #pragma unroll
    for (int mi = 0; mi < 8; ++mi) {
        #pragma unroll
        for (int nj = 0; nj < 4; ++nj) {
            const long row = (long)y * 256 + mi * 32 + wm * 16 + quad * 4;
            const long col = (long)x * 256 + nj * 64 + wn * 16 + l16;
            #pragma unroll
            for (int rr = 0; rr < 4; ++rr) {
                const float v = job.alpha * acc[mi][nj][rr];
                if constexpr (sizeof(TC) == 4)
                    C[(row + rr) * ldc + col] = v;
                else
                    C[(row + rr) * ldc + col] = f2bf(v);
                if constexpr (STATS) {
                    const long gr = row + rr;
                    if (gr < 896)          { s0 += v; ss0 += v * v; }
                    else if (gr < KVD)     { s1 += v; ss1 += v * v; }
                }
            }
        }
    }
    if constexpr (STATS) {
        __syncthreads();
        float* red = (float*)&AT[0][0][0][0];
        red[tid] = s0; red[512 + tid] = ss0; red[1024 + tid] = s1; red[1536 + tid] = ss1;
        __syncthreads();
        for (int o = 256; o > 0; o >>= 1) {
            if (tid < o) {
                red[tid]        += red[tid + o];
                red[512 + tid]  += red[512 + tid + o];
                red[1024 + tid] += red[1024 + tid + o];
                red[1536 + tid] += red[1536 + tid + o];
            }
            __syncthreads();
        }
        if (tid == 0) {
            const int m0g = y * 256;
            const int bA = (m0g >= 768) ? 1 : (m0g >= 512) ? 2 : 3;
            atomicAdd(&statsAcc[((long)z * 4 + bA) * 2],     red[0]);
            atomicAdd(&statsAcc[((long)z * 4 + bA) * 2 + 1], red[512]);
            if (y == 3) {   // rows 896..959 -> branch 0 (df=64)
                atomicAdd(&statsAcc[((long)z * 4 + 0) * 2],     red[1024]);
                atomicAdd(&statsAcc[((long)z * 4 + 0) * 2 + 1], red[1536]);
            }
        }
    }
}

// ---- softmax over real 960 cols; stats finalize inlined (reads atomic sums).
__global__ void softmax_kernel(const float* __restrict__ S,
                               short* __restrict__ Sa,
                               const float* __restrict__ acc)
{
    const int row = blockIdx.x;          // 0..1023 concat rows (>=960 = pad)
    const int y   = blockIdx.y;
    const int t   = threadIdx.x;
    short* orow = Sa + ((long)y * ECAT + row) * KVP;
    if (row >= KVD) {                    // zero pad row (clean B-operand for Ch)
        *(short4e*)(orow + 4 * t) = (short4e){0, 0, 0, 0};
        return;
    }
    const int bidx = (row >= 896) ? 0 : (row >= 768) ? 1 : (row >= 512) ? 2 : 3;
    const int dftab[4] = {64, 128, 256, 512};
    const float sum0 = acc[((long)y * 4 + bidx) * 2];
    const float ssq0 = acc[((long)y * 4 + bidx) * 2 + 1];
    const float n    = (float)(dftab[bidx] * KVD);
    const float mean = sum0 / n;
    const float rstd = rsqrtf(ssq0 / n - mean * mean + EPS);
    const float* srow = S + ((long)y * ECAT + row) * KVP;

    const bool real = (t < KVD / 4);     // threads 0..239 hold real cols (4 each)
    float x[4];
    float mx = -1e30f;
    if (real) {
        const float4 v = *(const float4*)(srow + 4 * t);
        x[0] = (v.x - mean) * rstd; x[1] = (v.y - mean) * rstd;
        x[2] = (v.z - mean) * rstd; x[3] = (v.w - mean) * rstd;
        mx = fmaxf(fmaxf(x[0], x[1]), fmaxf(x[2], x[3]));
    }
    __shared__ float red[256];
    red[t] = mx; __syncthreads();
    for (int o = 128; o > 0; o >>= 1) {
        if (t < o) red[t] = fmaxf(red[t], red[t + o]);
        __syncthreads();
    }
    mx = red[0];
    __syncthreads();

    float e[4] = {0.f, 0.f, 0.f, 0.f};
    float sum = 0.f;
    if (real) {
        e[0] = __expf(x[0] - mx); e[1] = __expf(x[1] - mx);
        e[2] = __expf(x[2] - mx); e[3] = __expf(x[3] - mx);
        sum = e[0] + e[1] + e[2] + e[3];
    }
    red[t] = sum; __syncthreads();
    for (int o = 128; o > 0; o >>= 1) {
        if (t < o) red[t] += red[t + o];
        __syncthreads();
    }
    const float inv = 1.0f / red[0];
    short4e o4;
    o4[0] = f2bf(e[0] * inv); o4[1] = f2bf(e[1] * inv);
    o4[2] = f2bf(e[2] * inv); o4[3] = f2bf(e[3] * inv);
    *(short4e*)(orow + 4 * t) = o4;
}

// ---------------------------------------------------------------------------
extern "C" void kernel_launch(void* const* d_in, const int* in_sizes, int n_in,
                              void* d_out, int out_size, void* d_ws, size_t ws_size,
                              hipStream_t stream)
{
    (void)in_sizes; (void)n_in; (void)out_size;
    const float* emb[4]  = {(const float*)d_in[0], (const float*)d_in[1],
                            (const float*)d_in[2], (const float*)d_in[3]};
    const float* emb_all = (const float*)d_in[4];
    const float* WQ[4]   = {(const float*)d_in[5], (const float*)d_in[6],
                            (const float*)d_in[7], (const float*)d_in[8]};
    const float* WK      = (const float*)d_in[9];
    const float* WV      = (const float*)d_in[10];
    const float* WO[4]   = {(const float*)d_in[11], (const float*)d_in[12],
                            (const float*)d_in[13], (const float*)d_in[14]};
    float* out = (float*)d_out;

    const int dfs[4]    = {64, 128, 256, 512};
    const int rowoff[4] = {896, 768, 512, 0};   // concat offsets (tile-aligned)
    const long N = NSEQ;

    // ---- workspace budget (Sacat aliases KT+Qcat; Chcat aliases Scat)
    const long eAll = (long)BATCH * N * KVD;
    const long eWKp = (long)HH * KVP * KVD;
    long preBytes = eAll * 2 + 2 * eWKp * 2;
    for (int br = 0; br < 4; ++br)
        preBytes += ((long)BATCH * N * dfs[br] + (long)HH * dfs[br] * dfs[br]
                    + (long)dfs[br] * dfs[br]) * 2;
    const long perG = (long)HH * KVP * N * 2
                    + (long)HH * ECAT * N * 2
                    + (long)HH * N * KVP * 2
                    + (long)HH * ECAT * KVP * 4;
    int G = 8;
    while (G > 1 && preBytes + (long)G * perG + 65536 > (long)ws_size) G >>= 1;

    // ---- carve workspace (KTb and Qb contiguous: Sab aliases their union)
    char* p = (char*)d_ws;
    short* embAllp = (short*)p; p += eAll * 2;
    short* embp[4]; short* WQp[4]; short* WOp[4];
    for (int br = 0; br < 4; ++br) { embp[br] = (short*)p; p += (long)BATCH * N * dfs[br] * 2; }
    for (int br = 0; br < 4; ++br) { WQp[br]  = (short*)p; p += (long)HH * dfs[br] * dfs[br] * 2; }
    short* WKp = (short*)p; p += eWKp * 2;
    short* WVp = (short*)p; p += eWKp * 2;
    for (int br = 0; br < 4; ++br) { WOp[br]  = (short*)p; p += (long)dfs[br] * dfs[br] * 2; }
    short* KTb = (short*)p; p += (long)G * HH * KVP * N * 2;
    short* Qb  = (short*)p; p += (long)G * HH * ECAT * N * 2;    // Qcat
    short* Vb  = (short*)p; p += (long)G * HH * N * KVP * 2;
    float* Sb  = (float*)p; p += (long)G * HH * ECAT * KVP * 4;  // Scat
    float* statsAcc = (float*)p; p += (long)BATCH * HH * 4 * 2 * 4;
    short* Sab = (short*)KTb;  // Sacat aliases KT+Qcat (dead after S GEMM)
    short* Chb = (short*)Sb;   // Chcat aliases Scat (dead after softmax)

    // ---- ONE convert launch: 13 plain segments + 2 padded-W segments
    {
        ConvJobs J;
        long cum = 0; int sg = 0;
        auto addJob = [&](const float* src, short* dst, long nunits, int ty) {
            J.src[sg] = src; J.dst[sg] = dst; J.cum[sg] = cum; J.type[sg] = ty;
            cum += nunits; ++sg;
        };
        addJob(emb_all, embAllp, eAll / 8, 0);
        for (int br = 0; br < 4; ++br) addJob(emb[br], embp[br], (long)BATCH * N * dfs[br] / 8, 0);
        for (int br = 0; br < 4; ++br) addJob(WQ[br], WQp[br], (long)HH * dfs[br] * dfs[br] / 8, 0);
        for (int br = 0; br < 4; ++br) addJob(WO[br], WOp[br], (long)dfs[br] * dfs[br] / 8, 0);
        addJob(WK, WKp, (long)HH * KVP * (KVD / 8), 1);
        addJob(WV, WVp, (long)HH * KVP * (KVD / 8), 1);
        J.cum[15] = cum;
        J.statsAcc = statsAcc;
        J.nAcc = BATCH * HH * 4 * 2;
        conv_all_kernel<<<dim3((unsigned)((cum + 255) / 256)), dim3(256), 0, stream>>>(J);
    }

    const float scale = 1.0f / sqrtf((float)KVD);
    long outBase[4];
    {
        long acc = 0;
        for (int br = 0; br < 4; ++br) { outBase[br] = acc; acc += (long)BATCH * N * dfs[br]; }
    }

    const dim3 blk(256), blk8(512);
    int it = 0;
    for (int b0 = 0; b0 < BATCH; b0 += G, ++it) {
        const int Z = G * HH;
        const short* embA = embAllp + (long)b0 * N * KVD;
        float* accIt = statsAcc + (long)it * Z * 4 * 2;

        // ---- mega1 on mfma8: KT + V + Q512 + Q256 (one job table) -------------
        {
            GemmJobs J; int nj = 0; int base = 0;
            auto add8 = [&](const short* A, const short* B, void* C, float alpha,
                            int lda, int ldb, int ldc, int K,
                            long zAh, long zAg, long zBh, long zBg,
                            long zCh, long zCg, int gx, int gy) {
                GemmJob& q = J.j[nj];
                q.A = A; q.B = B; q.C = C; q.alpha = alpha;
                q.lda = lda; q.ldb = ldb; q.ldc = ldc; q.K = K; q.inner = 1;
                q.sA = 0; q.sB = 0;
                q.zAh = zAh; q.zAg = zAg; q.zBh = zBh; q.zBg = zBg;
                q.zCh = zCh; q.zCg = zCg;
                q.splitH = 1; q.gx = gx; q.gy = gy; q.Z = Z; q.cfg = 0;
                q.blkBase = base;
                base += gx * gy * Z; ++nj;
            };
            // KT[g][h][j(1024)][n] = sum_k WKp[h][j][k] embA[g][n][k]
            add8(WKp, embA, KTb, 1.0f, KVD, KVD, (int)N, KVD,
                 (long)KVP * KVD, 0, 0, (long)N * KVD,
                 (long)KVP * N, (long)HH * KVP * N, 4, 4);
            // V[g][h][n][j(1024)] = sum_k embA[g][n][k] WVp[h][j][k]
            add8(embA, WVp, Vb, 1.0f, KVD, KVD, KVP, KVD,
                 0, (long)N * KVD, (long)KVP * KVD, 0,
                 (long)N * KVP, (long)HH * N * KVP, 4, 4);
            // Q512: M=512 (gy=2) -> concat rows 0..511
            add8(WQp[3], embp[3] + (long)b0 * N * 512, Qb + (long)rowoff[3] * N, 1.0f,
                 512, 512, (int)N, 512,
                 512L * 512, 0, 0, (long)N * 512,
                 (long)ECAT * N, (long)HH * ECAT * N, 4, 2);
            // Q256: M=256 (gy=1) -> concat rows 512..767
            add8(WQp[2], embp[2] + (long)b0 * N * 256, Qb + (long)rowoff[2] * N, 1.0f,
                 256, 256, (int)N, 256,
                 256L * 256, 0, 0, (long)N * 256,
                 (long)ECAT * N, (long)HH * ECAT * N, 4, 1);
            J.njobs = nj;
            mfma8<short, 0><<<dim3(base), blk8, 0, stream>>>(J, nullptr);
        }

        // ---- Q128 + Q64 (legacy job-table) -> concat rows of Qcat -------------
        {
            GemmJobs J; int nj = 0; int base = 0;
            for (int br = 1; br >= 0; --br) {
                const int df = dfs[br];
                const short* embB = embp[br] + (long)b0 * N * df;
                short* Qdst = Qb + (long)rowoff[br] * N;
                GemmJob& q = J.j[nj];
                q.A = WQp[br]; q.B = embB; q.C = Qdst; q.alpha = 1.0f;
                q.lda = df; q.ldb = df; q.ldc = (int)N; q.K = df; q.inner = 1;
                q.sA = 0; q.sB = 0;
                q.zAh = (long)df * df; q.zAg = 0;
                q.zBh = 0;             q.zBg = (long)N * df;
                q.zCh = (long)ECAT * N; q.zCg = (long)HH * ECAT * N;
                q.splitH = 1; q.Z = Z; q.gx = 8; q.gy = 1;
                q.cfg = (df >= 128) ? 0 : 2;
                q.blkBase = base;
                base += 8 * Z;
                ++nj;
            }
            J.njobs = nj;
            mfma_jt<short><<<dim3(base), blk, 0, stream>>>(J);
        }

        // ---- S on mfma8 (fused instance-norm stats) ---------------------------
        {
            GemmJobs J; J.njobs = 1;
            GemmJob& s = J.j[0];
            s.A = Qb; s.B = KTb; s.C = Sb; s.alpha = scale;
            s.lda = (int)N; s.ldb = (int)N; s.ldc = KVP; s.K = (int)N; s.inner = 1;
            s.sA = 0; s.sB = 0;
            s.zAh = (long)ECAT * N;  s.zAg = (long)HH * ECAT * N;
            s.zBh = (long)KVP * N;   s.zBg = (long)HH * KVP * N;
            s.zCh = (long)ECAT * KVP; s.zCg = (long)HH * ECAT * KVP;
            s.splitH = 1; s.gx = 4; s.gy = 4; s.Z = Z; s.cfg = 0; s.blkBase = 0;
            mfma8<float, 1><<<dim3(16 * Z), blk8, 0, stream>>>(J, accIt);
        }

        // softmax (stats finalize inlined); writes Sab over dead KT+Qcat
        softmax_kernel<<<dim3(ECAT, Z), dim3(256), 0, stream>>>(Sb, Sab, accIt);

        // ---- Ch on mfma8 ------------------------------------------------------
        {
            GemmJobs J; J.njobs = 1;
            GemmJob& c = J.j[0];
            c.A = Vb; c.B = Sab; c.C = Chb; c.alpha = 1.0f;
            c.lda = KVP; c.ldb = KVP; c.ldc = ECAT; c.K = KVP; c.inner = 1;
            c.sA = 0; c.sB = 0;
            c.zAh = (long)N * KVP;   c.zAg = (long)HH * N * KVP;
            c.zBh = (long)ECAT * KVP; c.zBg = (long)HH * ECAT * KVP;
            c.zCh = (long)N * ECAT;  c.zCg = (long)HH * N * ECAT;
            c.splitH = 1; c.gx = 4; c.gy = 4; c.Z = Z; c.cfg = 0; c.blkBase = 0;
            mfma8<short, 0><<<dim3(16 * Z), blk8, 0, stream>>>(J, nullptr);
        }

        // ---- O mega-launch: 4 branches, one job table (legacy) ----------------
        {
            GemmJobs J; int nj = 0; int base = 0;
            for (int br = 3; br >= 0; --br) {
                const int df = dfs[br];
                const short* Asrc = Chb + rowoff[br];
                float* Cout = out + outBase[br] + (long)b0 * N * df;
                GemmJob& q = J.j[nj];
                q.A = Asrc; q.B = WOp[br]; q.C = Cout; q.alpha = 1.0f / HH;
                q.lda = ECAT; q.ldb = df; q.ldc = df; q.K = df; q.inner = HH;
                q.sA = (long)N * ECAT; q.sB = 0;
                q.zAh = 0; q.zAg = (long)HH * N * ECAT; q.zBh = 0; q.zBg = 0;
                q.zCh = 0; q.zCg = (long)N * df;
                q.splitH = 0; q.Z = G; q.gy = 8;
                if (df >= 128) { q.cfg = 0; q.gx = df / 128; }
                else           { q.cfg = 1; q.gx = 1;        }
                q.blkBase = base;
                base += q.gx * q.gy * G;
                ++nj;
            }
            J.njobs = nj;
            mfma_jt<float><<<dim3(base), blk, 0, stream>>>(J);
        }
    }
}